// Round 22
// baseline (911.205 us; speedup 1.0000x reference)
//
#include <hip/hip_runtime.h>

typedef __attribute__((ext_vector_type(8))) short short8;
typedef __attribute__((ext_vector_type(4))) short short4v;
typedef __attribute__((ext_vector_type(4))) float floatx4;

__device__ __forceinline__ float b2f(short b) {
  union { unsigned u; float f; } v; v.u = ((unsigned)(unsigned short)b) << 16; return v.f;
}
__device__ __forceinline__ short f2b(float f) {
  union { float f; unsigned u; } v; v.f = f;
  return (short)((v.u + 0x7fffu + ((v.u >> 16) & 1u)) >> 16);
}
// packed f32x2 -> bf16x2 (RNE), single VOP3 instr
__device__ __forceinline__ unsigned cvtpk(float lo, float hi) {
  unsigned r;
  asm("v_cvt_pk_bf16_f32 %0, %1, %2" : "=v"(r) : "v"(lo), "v"(hi));
  return r;
}
__device__ __forceinline__ float loadf(const void* p, size_t i, bool f32) {
  return f32 ? ((const float*)p)[i] : b2f(((const short*)p)[i]);
}
__device__ __forceinline__ short8 load8(const void* p, size_t i, bool f32) {
  if (f32) {
    const float* fp = (const float*)p + i;
    float4 a = *(const float4*)fp;
    float4 b = *(const float4*)(fp + 4);
    short8 r;
    r[0] = f2b(a.x); r[1] = f2b(a.y); r[2] = f2b(a.z); r[3] = f2b(a.w);
    r[4] = f2b(b.x); r[5] = f2b(b.y); r[6] = f2b(b.z); r[7] = f2b(b.w);
    return r;
  }
  return *(const short8*)((const short*)p + i);
}

// async global->LDS, 16B per lane. LDS dest = wave-uniform base + lane*16.
__device__ __forceinline__ void gload16(const short* g, short* l) {
  __builtin_amdgcn_global_load_lds(
      (const __attribute__((address_space(1))) unsigned int*)g,
      (__attribute__((address_space(3))) unsigned int*)l, 16, 0, 0);
}

// ---------- dtype detector (stamp logic removed: workspace is re-poisoned
// per iteration, R21 null result)
__global__ void detect_dtype(const unsigned short* __restrict__ w, int* __restrict__ flag) {
  __shared__ int cnt;
  if (threadIdx.x == 0) cnt = 0;
  __syncthreads();
  int bad = 0;
  for (int i = threadIdx.x; i < 4096; i += 256) {
    int e = (w[i] >> 7) & 0xFF;
    if (e >= 0xC8) bad++;
  }
  atomicAdd(&cnt, bad);
  __syncthreads();
  if (threadIdx.x == 0) *flag = (cnt > 64) ? 1 : 0;
}

// ---------- one-time dtype normalization: two sources -> one contiguous dst
__global__ __launch_bounds__(256)
void cvt_bf16_2(const void* __restrict__ srcA, long n8A,
                const void* __restrict__ srcB, long n8B,
                short* __restrict__ dst, const int* __restrict__ dflag) {
  const bool f32 = (*dflag != 0);
  const long n8 = n8A + n8B;
  long stride = (long)gridDim.x * 256;
  for (long i = (long)blockIdx.x * 256 + threadIdx.x; i < n8; i += stride) {
    const void* s; long e;
    if (i < n8A) { s = srcA; e = i * 8; } else { s = srcB; e = (i - n8A) * 8; }
    if (f32) {
      const float* fp = (const float*)s + e;
      float4 a = *(const float4*)fp;
      float4 b = *(const float4*)(fp + 4);
      short8 r;
      r[0] = f2b(a.x); r[1] = f2b(a.y); r[2] = f2b(a.z); r[3] = f2b(a.w);
      r[4] = f2b(b.x); r[5] = f2b(b.y); r[6] = f2b(b.z); r[7] = f2b(b.w);
      *(short8*)(dst + i * 8) = r;
    } else {
      *(short8*)(dst + i * 8) = *(const short8*)((const short*)s + e);
    }
  }
}

// ---------- cvt_tw: all 4 weight transposes in ONE launch (1-D grid decode).
__global__ __launch_bounds__(256)
void cvt_tw(const void* __restrict__ wq, short* __restrict__ wqd,
            const void* __restrict__ waq, short* __restrict__ waqd,
            const void* __restrict__ wo, short* __restrict__ wod,
            const void* __restrict__ wao, short* __restrict__ waod,
            const int* __restrict__ dflag) {
  __shared__ short st[64][72];
  const bool f32 = (*dflag != 0);
  const int K = 3072;
  int b = blockIdx.x;
  const void* src; short* dst; int N, n0, k0;
  if (b < 13824) {
    src = (b < 6912) ? wq : waq;
    dst = (b < 6912) ? wqd : waqd;
    int rem = b % 6912;
    N = 9216; n0 = (rem % 144) << 6; k0 = (rem / 144) << 6;
  } else {
    b -= 13824;
    src = (b < 2304) ? wo : wao;
    dst = (b < 2304) ? wod : waod;
    int rem = b % 2304;
    N = 3072; n0 = (rem % 48) << 6; k0 = (rem / 48) << 6;
  }
  const int c4 = threadIdx.x & 15;
  const int rq = threadIdx.x >> 4;
#pragma unroll
  for (int r = 0; r < 4; ++r) {
    int k = r * 16 + rq;
    int n = c4 * 4;
    short v0, v1, v2, v3;
    if (f32) {
      const float* sp = (const float*)src + (size_t)(k0 + k) * N + n0 + n;
      float4 f = *(const float4*)sp;
      v0 = f2b(f.x); v1 = f2b(f.y); v2 = f2b(f.z); v3 = f2b(f.w);
    } else {
      const short* sp = (const short*)src + (size_t)(k0 + k) * N + n0 + n;
      short4v s = *(const short4v*)sp;
      v0 = s[0]; v1 = s[1]; v2 = s[2]; v3 = s[3];
    }
    st[n + 0][k] = v0; st[n + 1][k] = v1; st[n + 2][k] = v2; st[n + 3][k] = v3;
  }
  __syncthreads();
  const int n = threadIdx.x >> 2;
  const int kc = (threadIdx.x & 3) << 4;
  short8 a = *(const short8*)(&st[n][kc]);
  short8 bb = *(const short8*)(&st[n][kc + 8]);
  short* dp = dst + (size_t)(n0 + n) * K + k0 + kc;
  *(short8*)(dp) = a;
  *(short8*)(dp + 8) = bb;
}

// ---------- rope_tab: cos/sin table rt[t][p], t<2560, p<64. 1.3 MB (parked in
// the attnB region, which is dead until attn_fa). Same trig as old norm_rope.
__global__ __launch_bounds__(256)
void rope_tab(const int* __restrict__ ids, float2* __restrict__ rt) {
  int idx = blockIdx.x * 256 + threadIdx.x;   // 640 blocks x 256 = 163840
  int t = idx >> 6, p = idx & 63;
  int axis; float expo;
  if (p < 8)       { axis = 0; expo = (float)(2 * p) * (1.0f / 16.0f); }
  else if (p < 36) { axis = 1; expo = (float)(2 * (p - 8)) * (1.0f / 56.0f); }
  else             { axis = 2; expo = (float)(2 * (p - 36)) * (1.0f / 56.0f); }
  float freq = __expf(-expo * 9.210340371976184f);
  float ang = (float)ids[t * 3 + axis] * freq;
  float s, c; sincosf(ang, &s, &c);
  rt[idx] = make_float2(c, s);
}

// ---------- OLD GEMM (fallback) ----------
__global__ __launch_bounds__(256, 2)
void gemm_bt(const void* __restrict__ A, int a_row0,
             const void* __restrict__ B, const void* __restrict__ bias,
             void* __restrict__ C, int c_row0, int N, int K,
             const int* __restrict__ dflag, int aIn, int cOut) {
  __shared__ short As[128 * 32];
  __shared__ short Bs[128 * 32];
  const bool f32 = (*dflag != 0);
  const bool a32 = aIn && f32;
  const bool c32 = cOut && f32;
  const int tid = threadIdx.x;
  const int lane = tid & 63, w = tid >> 6;
  const int wm = w & 1, wn = w >> 1;
  const int qg = lane >> 4, l16 = lane & 15;
  const int m0 = blockIdx.y << 7, n0 = blockIdx.x << 7;

  const int arow = tid >> 2, ak = (tid & 3) << 3;
  const int brow = tid >> 4, bc = (tid & 15) << 3;
  const int rot = tid & 15;

  floatx4 acc[4][4];
#pragma unroll
  for (int i = 0; i < 4; ++i)
#pragma unroll
    for (int j = 0; j < 4; ++j) acc[i][j] = (floatx4){0.f, 0.f, 0.f, 0.f};

  for (int k0 = 0; k0 < K; k0 += 32) {
    __syncthreads();
#pragma unroll
    for (int j = 0; j < 2; ++j) {
      short8 av = load8(A, (size_t)(a_row0 + m0 + j * 64 + arow) * K + (k0 + ak), a32);
      *(short8*)(As + (j * 64 + arow) * 32 + ak) = av;
      int kr = j * 16 + brow;
      short8 bv = load8(B, (size_t)(k0 + kr) * N + (n0 + bc), f32);
      int kq = kr >> 3, kj = kr & 7;
#pragma unroll
      for (int s = 0; s < 8; ++s) {
        int u = (s + rot) & 7;
        int n = bc + u;
        Bs[(n << 5) + ((kq ^ (n & 3)) << 3) + kj] = bv[u];
      }
    }
    __syncthreads();
    short8 a[4];
#pragma unroll
    for (int mi = 0; mi < 4; ++mi)
      a[mi] = *(const short8*)(As + (wm * 64 + mi * 16 + l16) * 32 + qg * 8);
#pragma unroll
    for (int ni = 0; ni < 4; ++ni) {
      int n = wn * 64 + ni * 16 + l16;
      short8 b = *(const short8*)(Bs + (n << 5) + ((qg ^ (n & 3)) << 3));
#pragma unroll
      for (int mi = 0; mi < 4; ++mi)
        acc[mi][ni] = __builtin_amdgcn_mfma_f32_16x16x32_bf16(a[mi], b, acc[mi][ni], 0, 0, 0);
    }
  }
#pragma unroll
  for (int ni = 0; ni < 4; ++ni) {
    int col = n0 + wn * 64 + ni * 16 + l16;
    float bv = bias ? loadf(bias, col, f32) : 0.0f;
#pragma unroll
    for (int mi = 0; mi < 4; ++mi) {
      int row = m0 + wm * 64 + mi * 16 + qg * 4;
#pragma unroll
      for (int r = 0; r < 4; ++r) {
        size_t idx = (size_t)(c_row0 + row + r) * N + col;
        float val = acc[mi][ni][r] + bv;
        if (c32) ((float*)C)[idx] = val;
        else     ((short*)C)[idx] = f2b(val);
      }
    }
  }
}

// ---------- old norm_rope (fallback path only)
__global__ __launch_bounds__(512)
void norm_rope(short* __restrict__ qkv, const int* __restrict__ ids,
               const void* __restrict__ nqw, const void* __restrict__ nkw,
               const void* __restrict__ naqw, const void* __restrict__ nakw,
               const int* __restrict__ dflag) {
  const bool f32 = (*dflag != 0);
  const int t = blockIdx.x, wv = threadIdx.x >> 6, lane = threadIdx.x & 63;
  const bool txt = t < 512;
  int p = lane, axis; float expo;
  if (p < 8)       { axis = 0; expo = (float)(2 * p) * (1.0f / 16.0f); }
  else if (p < 36) { axis = 1; expo = (float)(2 * (p - 8)) * (1.0f / 56.0f); }
  else             { axis = 2; expo = (float)(2 * (p - 36)) * (1.0f / 56.0f); }
  float freq = __expf(-expo * 9.210340371976184f);
  float ang = (float)ids[t * 3 + axis] * freq;
  float s, c; sincosf(ang, &s, &c);
  const void* qw = txt ? naqw : nqw;
  const void* kw = txt ? nakw : nkw;
  float w0q = loadf(qw, 2 * lane, f32), w1q = loadf(qw, 2 * lane + 1, f32);
  float w0k = loadf(kw, 2 * lane, f32), w1k = loadf(kw, 2 * lane + 1, f32);
  const float QS = 0.08838834764831845f * 1.4426950408889634f;
#pragma unroll
  for (int i = 0; i < 3; ++i) {
    int h = wv + 8 * i;
    short* qp = qkv + (size_t)t * 9216 + h * 128 + 2 * lane;
    short* kp = qp + 3072;
    union { unsigned u; short sh[2]; } qv, kv;
    qv.u = *(const unsigned*)qp;
    kv.u = *(const unsigned*)kp;
    float q0 = b2f(qv.sh[0]), q1 = b2f(qv.sh[1]);
    float k0 = b2f(kv.sh[0]), k1 = b2f(kv.sh[1]);
    float sq = q0 * q0 + q1 * q1, sk = k0 * k0 + k1 * k1;
#pragma unroll
    for (int o = 1; o < 64; o <<= 1) { sq += __shfl_xor(sq, o); sk += __shfl_xor(sk, o); }
    float rq = rsqrtf(sq * (1.0f / 128.0f) + 1e-5f);
    float rk = rsqrtf(sk * (1.0f / 128.0f) + 1e-5f);
    float qn0 = q0 * rq * w0q, qn1 = q1 * rq * w1q;
    float kn0 = k0 * rk * w0k, kn1 = k1 * rk * w1k;
    float qo0 = qn0 * c - qn1 * s, qo1 = qn1 * c + qn0 * s;
    float ko0 = kn0 * c - kn1 * s, ko1 = kn1 * c + kn0 * s;
    union { unsigned u; short sh[2]; } qo, ko;
    qo.sh[0] = f2b(qo0 * QS);
    qo.sh[1] = f2b(qo1 * QS);
    ko.sh[0] = f2b(ko0); ko.sh[1] = f2b(ko1);
    *(unsigned*)qp = qo.u;
    *(unsigned*)kp = ko.u;
  }
}

// ---------- GEMM v12 (qkv): 256x128 block tile, 128x64 wave tile, depth-2
// pipeline, single barrier/K-step, counted vmcnt(6), coalesced epilogue,
// + FUSED RMSNorm+RoPE (nrm=1): each n-tile is exactly one head's d-panel
// (9216 = 72x128; bx<24 q, 24-47 k, 48+ v). RMS axis = tile width (cross-wave
// row-sums via 2KB LDS strip disjoint from wreg slices); RoPE partner is
// shfl_xor(.,1) (adjacent cols differ in l16 bit0); cos/sin from precomputed
// table (avoids per-element sincosf). Bias applied in-place BEFORE norm
// (reference order). Norm runs on f32 accumulators (closer to reference than
// the old bf16-roundtrip norm_rope).
__global__ __launch_bounds__(256, 2)
void gemm_bf2(const short* __restrict__ A,
              const short* __restrict__ BTa, const void* __restrict__ biasa,
              int a0a, int c0a, int nYa,
              const short* __restrict__ BTb, const void* __restrict__ biasb,
              int a0b, int c0b,
              void* __restrict__ C, int N, int K,
              const int* __restrict__ dflag, int cOut,
              int nrm, const float2* __restrict__ ropetab,
              const void* __restrict__ nqw, const void* __restrict__ nkw,
              const void* __restrict__ naqw, const void* __restrict__ nakw) {
  __shared__ short Ls[3 * 8192 + 3 * 4096];    // 72 KB
#define ASB(b) (Ls + (b) * 8192)
#define BSB(b) (Ls + 24576 + (b) * 4096)
  const bool f32 = (*dflag != 0);
  const bool c32 = cOut && f32;
  const int bx = blockIdx.x;
  const int y = blockIdx.y;
  const short* BT; const void* bias; int arow0, crow0;
  if (y < nYa) { BT = BTa; bias = biasa; arow0 = a0a + (y << 8); crow0 = c0a + (y << 8); }
  else { int my = y - nYa; BT = BTb; bias = biasb; arow0 = a0b + (my << 8); crow0 = c0b + (my << 8); }
  const int tid = threadIdx.x;
  const int lane = tid & 63, w = tid >> 6;
  const int wm = w & 1, wn = w >> 1;
  const int qg = lane >> 4, l16 = lane & 15;
  const int n0 = bx << 7;
  const int garow = lane >> 2;
  const int gcir = lane & 3;
  const int nk = K >> 5;
  const int swz = (gcir ^ (garow & 3) ^ (garow >> 2)) << 3;
  const short* Abase = A + (size_t)(arow0 + w * 64 + garow) * K + swz;
  const short* Bbase = BT + (size_t)(n0 + w * 32 + garow) * K + swz;
  const int rswz = (l16 & 3) ^ (l16 >> 2);

  floatx4 acc[8][4];
#pragma unroll
  for (int i = 0; i < 8; ++i)
#pragma unroll
    for (int j = 0; j < 4; ++j) acc[i][j] = (floatx4){0.f, 0.f, 0.f, 0.f};

  auto STAGE = [&](int buf, int k0) {
#pragma unroll
    for (int j = 0; j < 4; ++j)
      gload16(Abase + (size_t)j * 16 * K + k0, ASB(buf) + ((w * 4 + j) << 9));
#pragma unroll
    for (int j = 0; j < 2; ++j)
      gload16(Bbase + (size_t)j * 16 * K + k0, BSB(buf) + ((w * 2 + j) << 9));
  };

  STAGE(0, 0);
  if (nk > 1) STAGE(1, 32);

  int cb = 0;
  for (int t = 0; t < nk; ++t) {
    if (t + 1 < nk) {
      asm volatile("s_waitcnt vmcnt(6) lgkmcnt(0)" ::: "memory");
    } else {
      asm volatile("s_waitcnt vmcnt(0) lgkmcnt(0)" ::: "memory");
    }
    __builtin_amdgcn_s_barrier();
    if (t + 2 < nk) {
      int sb = (cb == 0) ? 2 : cb - 1;
      STAGE(sb, (t + 2) << 5);
    }
    short8 a[8], b[4];
#pragma unroll
    for (int mi = 0; mi < 8; ++mi) {
      int ra = wm * 128 + mi * 16 + l16;
      a[mi] = *(const short8*)(ASB(cb) + (ra << 5) + ((qg ^ rswz) << 3));
    }
#pragma unroll
    for (int ni = 0; ni < 4; ++ni) {
      int n = wn * 64 + ni * 16 + l16;
      b[ni] = *(const short8*)(BSB(cb) + (n << 5) + ((qg ^ rswz) << 3));
    }
    __builtin_amdgcn_s_setprio(1);
#pragma unroll
    for (int ni = 0; ni < 4; ++ni)
#pragma unroll
      for (int mi = 0; mi < 8; ++mi)
        acc[mi][ni] = __builtin_amdgcn_mfma_f32_16x16x32_bf16(a[mi], b[ni], acc[mi][ni], 0, 0, 0);
    __builtin_amdgcn_s_setprio(0);
    cb = (cb == 2) ? 0 : cb + 1;
  }
  __builtin_amdgcn_s_barrier();   // all MFMAs done; staging LDS free

  // ---- fused bias + RMSNorm + RoPE on f32 accumulators (qkv path only)
  if (nrm) {
    // bias in-place FIRST (reference: eqkv = enc@w + b, then rms_norm)
    if (bias) {
#pragma unroll
      for (int ni = 0; ni < 4; ++ni) {
        float bvv = loadf(bias, n0 + wn * 64 + ni * 16 + l16, f32);
#pragma unroll
        for (int mi = 0; mi < 8; ++mi)
#pragma unroll
          for (int r = 0; r < 4; ++r) acc[mi][ni][r] += bvv;
      }
    }
    if (bx < 48) {   // q or k head panel: norm + rope
      float* sums = (float*)(Ls + 20480);   // 256 rows x 2 partials (2KB), disjoint from wreg (<16384)
      const bool isq = (bx < 24);
      const bool txt = (crow0 < 512);       // uniform per block (256-row tiles)
      const void* nw = isq ? (txt ? naqw : nqw) : (txt ? nakw : nkw);
      // per-row partial sumsq over this wave's 64 cols
#pragma unroll
      for (int mi = 0; mi < 8; ++mi) {
#pragma unroll
        for (int r = 0; r < 4; ++r) {
          float ps = 0.f;
#pragma unroll
          for (int ni = 0; ni < 4; ++ni) { float v = acc[mi][ni][r]; ps += v * v; }
          ps += __shfl_xor(ps, 1); ps += __shfl_xor(ps, 2);
          ps += __shfl_xor(ps, 4); ps += __shfl_xor(ps, 8);
          if (l16 == 0) sums[(wm * 128 + mi * 16 + qg * 4 + r) * 2 + wn] = ps;
        }
      }
      asm volatile("s_waitcnt lgkmcnt(0)" ::: "memory");
      __builtin_amdgcn_s_barrier();
      const float QS = 0.08838834764831845f * 1.4426950408889634f;
      const float scl = isq ? QS : 1.0f;
#pragma unroll
      for (int mi = 0; mi < 8; ++mi) {
#pragma unroll
        for (int r = 0; r < 4; ++r) {
          int row = wm * 128 + mi * 16 + qg * 4 + r;
          float s2 = sums[row * 2] + sums[row * 2 + 1];
          float rr = rsqrtf(s2 * (1.0f / 128.0f) + 1e-5f);
          int tt = crow0 + row;
#pragma unroll
          for (int ni = 0; ni < 4; ++ni) {
            int col = wn * 64 + ni * 16 + l16;   // col == d (tile width = head dim)
            float wv = loadf(nw, col, f32);
            float vn = acc[mi][ni][r] * rr * wv;
            float vp = __shfl_xor(vn, 1);        // partner d^1 (same wave, l16 bit0)
            float2 cs = ropetab[tt * 64 + (col >> 1)];
            float sgn = (col & 1) ? 1.0f : -1.0f;
            acc[mi][ni][r] = (vn * cs.x + sgn * vp * cs.y) * scl;
          }
        }
      }
    }
  }

  const void* biasS = nrm ? nullptr : bias;   // nrm path applied bias already
  if (!c32) {
    short* wreg = Ls + w * 4096;
#pragma unroll
    for (int half = 0; half < 2; ++half) {
#pragma unroll
      for (int ni = 0; ni < 4; ++ni) {
        float bvv = biasS ? loadf(biasS, n0 + wn * 64 + ni * 16 + l16, f32) : 0.0f;
#pragma unroll
        for (int mi2 = 0; mi2 < 4; ++mi2)
#pragma unroll
          for (int r = 0; r < 4; ++r)
            wreg[(mi2 * 16 + qg * 4 + r) * 64 + ni * 16 + l16] =
                f2b(acc[half * 4 + mi2][ni][r] + bvv);
      }
      asm volatile("s_waitcnt lgkmcnt(0)" ::: "memory");
#pragma unroll
      for (int j = 0; j < 8; ++j) {
        int row = j * 8 + (lane >> 3);
        int col = (lane & 7) * 8;
        short8 v = *(const short8*)(wreg + row * 64 + col);
        *(short8*)((short*)C + (size_t)(crow0 + wm * 128 + half * 64 + row) * N +
                   n0 + wn * 64 + col) = v;
      }
      asm volatile("s_waitcnt lgkmcnt(0)" ::: "memory");
    }
  } else {
    float* wregf = (float*)(Ls) + w * 2048;
#pragma unroll
    for (int half = 0; half < 2; ++half) {
#pragma unroll
      for (int ch = 0; ch < 2; ++ch) {
#pragma unroll
        for (int nh = 0; nh < 2; ++nh) {
          int ni = ch * 2 + nh;
          float bvv = biasS ? loadf(biasS, n0 + wn * 64 + ni * 16 + l16, f32) : 0.0f;
#pragma unroll
          for (int mi2 = 0; mi2 < 4; ++mi2)
#pragma unroll
            for (int r = 0; r < 4; ++r)
              wregf[(mi2 * 16 + qg * 4 + r) * 32 + nh * 16 + l16] =
                  acc[half * 4 + mi2][ni][r] + bvv;
        }
        asm volatile("s_waitcnt lgkmcnt(0)" ::: "memory");
#pragma unroll
        for (int j = 0; j < 8; ++j) {
          int row = j * 8 + (lane >> 3);
          int c4 = (lane & 7) * 4;
          float4 v = *(const float4*)(wregf + row * 32 + c4);
          *(float4*)((float*)C + (size_t)(crow0 + wm * 128 + half * 64 + row) * N +
                     n0 + wn * 64 + ch * 32 + c4) = v;
        }
        asm volatile("s_waitcnt lgkmcnt(0)" ::: "memory");
      }
    }
  }
#undef ASB
#undef BSB
}

// ---------- GEMM v10 variant (out-proj): 128x128 tile, 3 blocks/CU.
__global__ __launch_bounds__(256, 3)
void gemm_bf128(const short* __restrict__ A,
                const short* __restrict__ BTa, const void* __restrict__ biasa,
                int a0a, int c0a, int nYa,
                const short* __restrict__ BTb, const void* __restrict__ biasb,
                int a0b, int c0b,
                void* __restrict__ C, int N, int K,
                const int* __restrict__ dflag, int cOut) {
  __shared__ short Ls[6 * 128 * 32];           // 48 KB
#define ASB(b) (Ls + (b) * 4096)
#define BSB(b) (Ls + (3 + (b)) * 4096)
  const bool f32 = (*dflag != 0);
  const bool c32 = cOut && f32;
  const int bx = blockIdx.x;
  const int y = blockIdx.y;
  const short* BT; const void* bias; int arow0, crow0;
  if (y < nYa) { BT = BTa; bias = biasa; arow0 = a0a + (y << 7); crow0 = c0a + (y << 7); }
  else { int my = y - nYa; BT = BTb; bias = biasb; arow0 = a0b + (my << 7); crow0 = c0b + (my << 7); }
  const int tid = threadIdx.x;
  const int lane = tid & 63, w = tid >> 6;
  const int wm = w & 1, wn = w >> 1;
  const int qg = lane >> 4, l16 = lane & 15;
  const int n0 = bx << 7;
  const int garow = lane >> 2;
  const int gcir = lane & 3;
  const int nk = K >> 5;
  const int swz = (gcir ^ (garow & 3) ^ (garow >> 2)) << 3;
  const short* Abase = A + (size_t)(arow0 + w * 32 + garow) * K + swz;
  const short* Bbase = BT + (size_t)(n0 + w * 32 + garow) * K + swz;
  const int rswz = (l16 & 3) ^ (l16 >> 2);

  floatx4 acc[4][4];
#pragma unroll
  for (int i = 0; i < 4; ++i)
#pragma unroll
    for (int j = 0; j < 4; ++j) acc[i][j] = (floatx4){0.f, 0.f, 0.f, 0.f};

  auto STAGE = [&](int buf, int k0) {
#pragma unroll
    for (int j = 0; j < 2; ++j) {
      gload16(Abase + (size_t)j * 16 * K + k0, ASB(buf) + ((w * 2 + j) << 9));
      gload16(Bbase + (size_t)j * 16 * K + k0, BSB(buf) + ((w * 2 + j) << 9));
    }
  };

  STAGE(0, 0);
  if (nk > 1) STAGE(1, 32);

  int cb = 0;
  for (int t = 0; t < nk; ++t) {
    if (t + 1 < nk) {
      asm volatile("s_waitcnt vmcnt(4) lgkmcnt(0)" ::: "memory");
    } else {
      asm volatile("s_waitcnt vmcnt(0) lgkmcnt(0)" ::: "memory");
    }
    __builtin_amdgcn_s_barrier();
    if (t + 2 < nk) {
      int sb = (cb == 0) ? 2 : cb - 1;
      STAGE(sb, (t + 2) << 5);
    }
    short8 a[4], b[4];
#pragma unroll
    for (int mi = 0; mi < 4; ++mi) {
      int ra = wm * 64 + mi * 16 + l16;
      a[mi] = *(const short8*)(ASB(cb) + (ra << 5) + ((qg ^ rswz) << 3));
    }
#pragma unroll
    for (int ni = 0; ni < 4; ++ni) {
      int n = wn * 64 + ni * 16 + l16;
      b[ni] = *(const short8*)(BSB(cb) + (n << 5) + ((qg ^ rswz) << 3));
    }
    __builtin_amdgcn_s_setprio(1);
#pragma unroll
    for (int ni = 0; ni < 4; ++ni)
#pragma unroll
      for (int mi = 0; mi < 4; ++mi)
        acc[mi][ni] = __builtin_amdgcn_mfma_f32_16x16x32_bf16(a[mi], b[ni], acc[mi][ni], 0, 0, 0);
    __builtin_amdgcn_s_setprio(0);
    cb = (cb == 2) ? 0 : cb + 1;
  }
  __builtin_amdgcn_s_barrier();
  if (!c32) {
    short* wreg = Ls + w * 4096;
#pragma unroll
    for (int ni = 0; ni < 4; ++ni) {
      float bvv = bias ? loadf(bias, n0 + wn * 64 + ni * 16 + l16, f32) : 0.0f;
#pragma unroll
      for (int mi = 0; mi < 4; ++mi)
#pragma unroll
        for (int r = 0; r < 4; ++r)
          wreg[(mi * 16 + qg * 4 + r) * 64 + ni * 16 + l16] = f2b(acc[mi][ni][r] + bvv);
    }
    asm volatile("s_waitcnt lgkmcnt(0)" ::: "memory");
#pragma unroll
    for (int j = 0; j < 8; ++j) {
      int row = j * 8 + (lane >> 3);
      int col = (lane & 7) * 8;
      short8 v = *(const short8*)(wreg + row * 64 + col);
      *(short8*)((short*)C + (size_t)(crow0 + wm * 64 + row) * N + n0 + wn * 64 + col) = v;
    }
  } else {
    float* wregf = (float*)(Ls) + w * 2048;
#pragma unroll
    for (int half = 0; half < 2; ++half) {
#pragma unroll
      for (int nh = 0; nh < 2; ++nh) {
        int ni = half * 2 + nh;
        float bvv = bias ? loadf(bias, n0 + wn * 64 + ni * 16 + l16, f32) : 0.0f;
#pragma unroll
        for (int mi = 0; mi < 4; ++mi)
#pragma unroll
          for (int r = 0; r < 4; ++r)
            wregf[(mi * 16 + qg * 4 + r) * 32 + nh * 16 + l16] = acc[mi][ni][r] + bvv;
      }
      asm volatile("s_waitcnt lgkmcnt(0)" ::: "memory");
#pragma unroll
      for (int j = 0; j < 8; ++j) {
        int row = j * 8 + (lane >> 3);
        int c4 = (lane & 7) * 4;
        float4 v = *(const float4*)(wregf + row * 32 + c4);
        *(float4*)((float*)C + (size_t)(crow0 + wm * 64 + row) * N + n0 + wn * 64 + half * 32 + c4) = v;
      }
      asm volatile("s_waitcnt lgkmcnt(0)" ::: "memory");
    }
  }
#undef ASB
#undef BSB
}

// ---------- flash attention v10 (measured-best: Q128/KB128, 2 blocks/CU,
// Pw pitch-32 + XOR).
__global__ __launch_bounds__(512, 2)
void attn_fa(const short* __restrict__ qkv, short* __restrict__ attn) {
  __shared__ short KVs[2][128 * 128];   // 64 KB: K tiles; V^T overwrites in place
  __shared__ short Pw[8][512];          // 8 KB: per-wave P chunk (16 rows x 32 keys)
  const int wgid = blockIdx.x;
  const int xcd = wgid & 7, slot = wgid >> 3;   // 60 slots/XCD
  const int h = xcd * 3 + slot / 20;            // 3 heads per XCD (L2-resident K/V)
  const int qt = slot % 20;
  const int tid = threadIdx.x, lane = tid & 63, w = tid >> 6;  // 8 waves
  const int qg = lane >> 4, l16 = lane & 15;
  const int lr = lane >> 4, lc = lane & 15;
  const int q0 = qt << 7;
  const int sc = tid & 15;
  const int srow5 = (tid >> 4) & 15, half = tid >> 8;

  const short* Qg  = qkv + (size_t)q0 * 9216 + h * 128;
  const short* Kg0 = qkv + 3072 + h * 128;
  const short* Vg0 = qkv + 6144 + h * 128;

  // ---- prologue: K(0) gloads FIRST (drained by vmcnt(8)), then Q regs, V regs
#pragma unroll
  for (int j = 0; j < 4; ++j) {
    int row = j * 32 + w * 4 + lr;
    gload16(Kg0 + (size_t)row * 9216 + ((lc ^ (row & 7)) << 3),
            &KVs[0][(j * 32 + w * 4) * 128]);
  }
  short8 aq[4];
#pragma unroll
  for (int kc = 0; kc < 4; ++kc)
    aq[kc] = *(const short8*)(Qg + (size_t)(w * 16 + l16) * 9216 + kc * 32 + qg * 8);
  short8 vr[4];
#pragma unroll
  for (int j = 0; j < 4; ++j) {
    int row = half * 64 + j * 16 + srow5;
    vr[j] = *(const short8*)(Vg0 + (size_t)row * 9216 + sc * 8);
  }
  asm volatile("s_waitcnt vmcnt(8) lgkmcnt(0)" ::: "memory");  // K(0) done; Q,V in flight
  __builtin_amdgcn_s_barrier();

  floatx4 acc_o[8];
#pragma unroll
  for (int nd = 0; nd < 8; ++nd) acc_o[nd] = (floatx4){0.f, 0.f, 0.f, 0.f};
  float m_i[4], l_i[4];
#pragma unroll
  for (int r = 0; r < 4; ++r) { m_i[r] = -1e30f; l_i[r] = 0.0f; }

  for (int kt = 0; kt < 20; ++kt) {
    const int cb = kt & 1;
    asm volatile("s_waitcnt vmcnt(4) lgkmcnt(0)" ::: "memory");  // K(kt) landed; V(kt) in flight
    __builtin_amdgcn_s_barrier();
    if (kt < 19) {
      const short* Kg = qkv + ((size_t)(kt + 1) * 128) * 9216 + 3072 + h * 128;
#pragma unroll
      for (int j = 0; j < 4; ++j) {
        int row = j * 32 + w * 4 + lr;
        gload16(Kg + (size_t)row * 9216 + ((lc ^ (row & 7)) << 3),
                &KVs[1 - cb][(j * 32 + w * 4) * 128]);
      }
    }
    // ---- QK^T: 16 q-rows x 128 keys (scores in log2 domain via q-scale)
    floatx4 acc_s[8];
#pragma unroll
    for (int ni = 0; ni < 8; ++ni) acc_s[ni] = (floatx4){0.f, 0.f, 0.f, 0.f};
    __builtin_amdgcn_s_setprio(1);
#pragma unroll
    for (int kc = 0; kc < 4; ++kc) {
#pragma unroll
      for (int ni = 0; ni < 8; ++ni) {
        int row = ni * 16 + l16;
        short8 b = *(const short8*)(&KVs[cb][row * 128 + (((kc * 4 + qg) ^ (row & 7)) << 3)]);
        acc_s[ni] = __builtin_amdgcn_mfma_f32_16x16x32_bf16(aq[kc], b, acc_s[ni], 0, 0, 0);
      }
    }
    __builtin_amdgcn_s_setprio(0);
    // ---- online softmax, exp2 domain, defer-rescale (T13)
    float mxv[4];
    bool need = false;
#pragma unroll
    for (int r = 0; r < 4; ++r) {
      float mx = acc_s[0][r];
#pragma unroll
      for (int ni = 1; ni < 8; ++ni) mx = fmaxf(mx, acc_s[ni][r]);
      mx = fmaxf(mx, __shfl_xor(mx, 1));
      mx = fmaxf(mx, __shfl_xor(mx, 2));
      mx = fmaxf(mx, __shfl_xor(mx, 4));
      mx = fmaxf(mx, __shfl_xor(mx, 8));
      mxv[r] = mx;
      need = need || (mx > m_i[r] + 8.0f);
    }
    if (__ballot(need)) {
#pragma unroll
      for (int r = 0; r < 4; ++r) {
        float mn = fmaxf(m_i[r], mxv[r]);
        float al = __builtin_amdgcn_exp2f(m_i[r] - mn);
        m_i[r] = mn;
        l_i[r] *= al;
#pragma unroll
        for (int nd = 0; nd < 8; ++nd) acc_o[nd][r] *= al;
      }
    }
    // pkr[r][kc]: bf16x2 of (pv[2kc], pv[2kc+1]) — P chunk kc, in-chunk t'=2*l16(+1)
    unsigned pkr[4][4];
#pragma unroll
    for (int r = 0; r < 4; ++r) {
      float pv[8];
      float rs = 0.f;
#pragma unroll
      for (int ni = 0; ni < 8; ++ni) {
        pv[ni] = __builtin_amdgcn_exp2f(acc_s[ni][r] - m_i[r]);
        rs += pv[ni];
      }
#pragma unroll
      for (int kc = 0; kc < 4; ++kc) pkr[r][kc] = cvtpk(pv[2 * kc], pv[2 * kc + 1]);
      rs += __shfl_xor(rs, 1); rs += __shfl_xor(rs, 2);
      rs += __shfl_xor(rs, 4); rs += __shfl_xor(rs, 8);
      l_i[r] += rs;
    }
    asm volatile("s_waitcnt lgkmcnt(0)" ::: "memory");
    __builtin_amdgcn_s_barrier();   // QK^T reads of KVs[cb] done
    // ---- commit V^T(kt) into KVs[cb]: token r -> chunk r>>5, in-chunk
    // t' = 2*(r&15) + ((r>>4)&1).
#pragma unroll
    for (int u = 0; u < 8; ++u) {
      int d = sc * 8 + u;
      int xr = (d & 7) ^ ((d >> 3) & 7);
#pragma unroll
      for (int jp = 0; jp < 2; ++jp) {
        int kcw = 2 * half + jp;
        int g = kcw * 4 + (srow5 >> 2);
        union { unsigned uu; short sh[2]; } pk;
        pk.sh[0] = vr[2 * jp][u]; pk.sh[1] = vr[2 * jp + 1][u];
        *(unsigned*)(&KVs[cb][d * 128 + ((g ^ xr) << 3) + ((2 * srow5) & 7)]) = pk.uu;
      }
    }
    if (kt < 19) {
      const short* Vg = qkv + ((size_t)(kt + 1) * 128) * 9216 + 6144 + h * 128;
#pragma unroll
      for (int j = 0; j < 4; ++j) {
        int row = half * 64 + j * 16 + srow5;
        vr[j] = *(const short8*)(Vg + (size_t)row * 9216 + sc * 8);
      }
    }
    asm volatile("s_waitcnt lgkmcnt(0)" ::: "memory");
    __builtin_amdgcn_s_barrier();
    // ---- PV: per kc spill P chunk to wave-private Pw, read A-frag, 8 MFMA.
    __builtin_amdgcn_s_setprio(1);
#pragma unroll
    for (int kc = 0; kc < 4; ++kc) {
#pragma unroll
      for (int r = 0; r < 4; ++r)
        *(unsigned*)(&Pw[w][(qg * 4 + r) * 32 + ((l16 ^ (qg << 2)) << 1)]) = pkr[r][kc];
      short8 ap = *(const short8*)(&Pw[w][l16 * 32 + ((qg ^ (l16 >> 2)) << 3)]);
#pragma unroll
      for (int nd = 0; nd < 8; ++nd) {
        int d = nd * 16 + l16;
        int chn = (kc * 4 + qg) ^ (d & 7) ^ ((d >> 3) & 7);
        short8 b = *(const short8*)(&KVs[cb][d * 128 + (chn << 3)]);
        acc_o[nd] = __builtin_amdgcn_mfma_f32_16x16x32_bf16(ap, b, acc_o[nd], 0, 0, 0);
      }
    }
    __builtin_amdgcn_s_setprio(0);
  }
  // ---- epilogue: normalize, transpose through KVs (freed), coalesced stores
  asm volatile("s_waitcnt lgkmcnt(0)" ::: "memory");
  __builtin_amdgcn_s_barrier();   // all PV reads done
  short* Es = &KVs[0][0];         // 128 rows x 128 shorts
  float inv[4];
#pragma unroll
  for (int r = 0; r < 4; ++r) inv[r] = 1.0f / l_i[r];
#pragma unroll
  for (int nd = 0; nd < 8; ++nd)
#pragma unroll
    for (int r = 0; r < 4; ++r) {
      int row = w * 16 + qg * 4 + r;
      Es[row * 128 + nd * 16 + l16] = f2b(acc_o[nd][r] * inv[r]);
    }
  asm volatile("s_waitcnt lgkmcnt(0)" ::: "memory");   // wave-private rows
#pragma unroll
  for (int j = 0; j < 4; ++j) {
    int rrow = w * 16 + j * 4 + qg;
    short8 vv = *(const short8*)(Es + rrow * 128 + l16 * 8);
    *(short8*)(attn + (size_t)(q0 + rrow) * 3072 + h * 128 + l16 * 8) = vv;
  }
}

extern "C" void kernel_launch(void* const* d_in, const int* in_sizes, int n_in,
                              void* d_out, int out_size, void* d_ws, size_t ws_size,
                              hipStream_t stream) {
  (void)in_sizes; (void)n_in; (void)out_size;
  const void* hidden    = d_in[0];
  const void* enc       = d_in[1];
  const int*  ids       = (const int*)d_in[2];
  const void* w_qkv     = d_in[3];
  const void* w_add_qkv = d_in[4];
  const void* b_add_qkv = d_in[5];
  const void* w_out     = d_in[6];
  const void* b_out     = d_in[7];
  const void* w_add_out = d_in[8];
  const void* b_add_out = d_in[9];
  const void* nqw  = d_in[10];
  const void* nkw  = d_in[11];
  const void* naqw = d_in[12];
  const void* nakw = d_in[13];

  int*   dflag = (int*)d_ws;
  short* qkv   = (short*)((char*)d_ws + 256);   // [2560][9216] bf16
  short* attnB = qkv + (size_t)2560 * 9216;     // [2560][3072] bf16

  short* pool  = attnB + (size_t)2560 * 3072;
  const long n_hid  = 2048L * 3072;
  const long n_enc  = 512L * 3072;
  const long n_wqkv = 3072L * 9216;
  const long n_wout = 3072L * 3072;
  short* xb   = pool;                    // [2560][3072]
  short* wqb  = xb + n_enc + n_hid;      // w_qkv^T    [9216][3072]
  short* waqb = wqb + n_wqkv;            // w_add_qkv^T[9216][3072]
  short* wob  = waqb + n_wqkv;           // w_out^T    [3072][3072]
  short* waob = wob + n_wout;            // w_add_out^T[3072][3072]
  const size_t REQ = 256 + 2 * ((size_t)2560 * 9216 + (size_t)2560 * 3072 +
                                n_hid + n_enc + 2 * n_wqkv + 2 * n_wout);

  // rope table parked in attnB (dead until attn_fa; only needed during qkv gemm)
  float2* rtab = (float2*)attnB;   // 2560*64*8 B = 1.31 MB << 15.7 MB

  detect_dtype<<<1, 256, 0, stream>>>((const unsigned short*)w_qkv, dflag);

  if (ws_size >= REQ) {
    cvt_bf16_2<<<1024, 256, 0, stream>>>(enc, n_enc / 8, hidden, n_hid / 8, xb, dflag);
    cvt_tw<<<dim3(18432), 256, 0, stream>>>(w_qkv, wqb, w_add_qkv, waqb,
                                            w_out, wob, w_add_out, waob, dflag);
    rope_tab<<<dim3(640), 256, 0, stream>>>(ids, rtab);

    // merged QKV projection + FUSED bias/RMSNorm/RoPE, 256-row tiles:
    // y<2 -> enc (bias), y>=2 -> hidden
    gemm_bf2<<<dim3(72, 10), 256, 0, stream>>>(
        xb, waqb, b_add_qkv, 0, 0, 2, wqb, nullptr, 512, 512,
        qkv, 9216, 3072, dflag, 0,
        1, rtab, nqw, nkw, naqw, nakw);
    // attention: 480 blocks = 24 heads x 20 q-tiles of 128, 2 blocks/CU
    // (attn_fa overwrites attnB, incl. the now-dead rope table region)
    attn_fa<<<dim3(480), 512, 0, stream>>>(qkv, attnB);
    // merged out-proj, 128-row tiles: y<16 img, y>=16 enc
    gemm_bf128<<<dim3(24, 20), 256, 0, stream>>>(
        attnB, wob, b_out, 512, 0, 16, waob, b_add_out, 0, 2048,
        d_out, 3072, 3072, dflag, 1);
  } else {
    gemm_bt<<<dim3(72, 4), 256, 0, stream>>>(enc, 0, w_add_qkv, b_add_qkv, qkv, 0, 9216, 3072, dflag, 1, 0);
    gemm_bt<<<dim3(72, 16), 256, 0, stream>>>(hidden, 0, w_qkv, nullptr, qkv, 512, 9216, 3072, dflag, 1, 0);
    norm_rope<<<dim3(2560), 512, 0, stream>>>(qkv, ids, nqw, nkw, naqw, nakw, dflag);
    attn_fa<<<dim3(480), 512, 0, stream>>>(qkv, attnB);
    gemm_bt<<<dim3(24, 16), 256, 0, stream>>>(attnB, 512, w_out, b_out, d_out, 0, 3072, 3072, dflag, 0, 1);
    gemm_bt<<<dim3(24, 4), 256, 0, stream>>>(attnB, 0, w_add_out, b_add_out, d_out, 2048, 3072, 3072, dflag, 0, 1);
  }
}

// Round 23
// 784.617 us; speedup vs baseline: 1.1613x; 1.1613x over previous
//
#include <hip/hip_runtime.h>

typedef __attribute__((ext_vector_type(8))) short short8;
typedef __attribute__((ext_vector_type(4))) short short4v;
typedef __attribute__((ext_vector_type(4))) float floatx4;

__device__ __forceinline__ float b2f(short b) {
  union { unsigned u; float f; } v; v.u = ((unsigned)(unsigned short)b) << 16; return v.f;
}
__device__ __forceinline__ short f2b(float f) {
  union { float f; unsigned u; } v; v.f = f;
  return (short)((v.u + 0x7fffu + ((v.u >> 16) & 1u)) >> 16);
}
// packed f32x2 -> bf16x2 (RNE), single VOP3 instr
__device__ __forceinline__ unsigned cvtpk(float lo, float hi) {
  unsigned r;
  asm("v_cvt_pk_bf16_f32 %0, %1, %2" : "=v"(r) : "v"(lo), "v"(hi));
  return r;
}
__device__ __forceinline__ float loadf(const void* p, size_t i, bool f32) {
  return f32 ? ((const float*)p)[i] : b2f(((const short*)p)[i]);
}
__device__ __forceinline__ short8 load8(const void* p, size_t i, bool f32) {
  if (f32) {
    const float* fp = (const float*)p + i;
    float4 a = *(const float4*)fp;
    float4 b = *(const float4*)(fp + 4);
    short8 r;
    r[0] = f2b(a.x); r[1] = f2b(a.y); r[2] = f2b(a.z); r[3] = f2b(a.w);
    r[4] = f2b(b.x); r[5] = f2b(b.y); r[6] = f2b(b.z); r[7] = f2b(b.w);
    return r;
  }
  return *(const short8*)((const short*)p + i);
}

// async global->LDS, 16B per lane. LDS dest = wave-uniform base + lane*16.
__device__ __forceinline__ void gload16(const short* g, short* l) {
  __builtin_amdgcn_global_load_lds(
      (const __attribute__((address_space(1))) unsigned int*)g,
      (__attribute__((address_space(3))) unsigned int*)l, 16, 0, 0);
}

// ---------- dtype detector
__global__ void detect_dtype(const unsigned short* __restrict__ w, int* __restrict__ flag) {
  __shared__ int cnt;
  if (threadIdx.x == 0) cnt = 0;
  __syncthreads();
  int bad = 0;
  for (int i = threadIdx.x; i < 4096; i += 256) {
    int e = (w[i] >> 7) & 0xFF;
    if (e >= 0xC8) bad++;
  }
  atomicAdd(&cnt, bad);
  __syncthreads();
  if (threadIdx.x == 0) *flag = (cnt > 64) ? 1 : 0;
}

// ---------- one-time dtype normalization: two sources -> one contiguous dst
__global__ __launch_bounds__(256)
void cvt_bf16_2(const void* __restrict__ srcA, long n8A,
                const void* __restrict__ srcB, long n8B,
                short* __restrict__ dst, const int* __restrict__ dflag) {
  const bool f32 = (*dflag != 0);
  const long n8 = n8A + n8B;
  long stride = (long)gridDim.x * 256;
  for (long i = (long)blockIdx.x * 256 + threadIdx.x; i < n8; i += stride) {
    const void* s; long e;
    if (i < n8A) { s = srcA; e = i * 8; } else { s = srcB; e = (i - n8A) * 8; }
    if (f32) {
      const float* fp = (const float*)s + e;
      float4 a = *(const float4*)fp;
      float4 b = *(const float4*)(fp + 4);
      short8 r;
      r[0] = f2b(a.x); r[1] = f2b(a.y); r[2] = f2b(a.z); r[3] = f2b(a.w);
      r[4] = f2b(b.x); r[5] = f2b(b.y); r[6] = f2b(b.z); r[7] = f2b(b.w);
      *(short8*)(dst + i * 8) = r;
    } else {
      *(short8*)(dst + i * 8) = *(const short8*)((const short*)s + e);
    }
  }
}

// ---------- cvt_tw: all 4 weight transposes in ONE launch (1-D grid decode).
__global__ __launch_bounds__(256)
void cvt_tw(const void* __restrict__ wq, short* __restrict__ wqd,
            const void* __restrict__ waq, short* __restrict__ waqd,
            const void* __restrict__ wo, short* __restrict__ wod,
            const void* __restrict__ wao, short* __restrict__ waod,
            const int* __restrict__ dflag) {
  __shared__ short st[64][72];
  const bool f32 = (*dflag != 0);
  const int K = 3072;
  int b = blockIdx.x;
  const void* src; short* dst; int N, n0, k0;
  if (b < 13824) {
    src = (b < 6912) ? wq : waq;
    dst = (b < 6912) ? wqd : waqd;
    int rem = b % 6912;
    N = 9216; n0 = (rem % 144) << 6; k0 = (rem / 144) << 6;
  } else {
    b -= 13824;
    src = (b < 2304) ? wo : wao;
    dst = (b < 2304) ? wod : waod;
    int rem = b % 2304;
    N = 3072; n0 = (rem % 48) << 6; k0 = (rem / 48) << 6;
  }
  const int c4 = threadIdx.x & 15;
  const int rq = threadIdx.x >> 4;
#pragma unroll
  for (int r = 0; r < 4; ++r) {
    int k = r * 16 + rq;
    int n = c4 * 4;
    short v0, v1, v2, v3;
    if (f32) {
      const float* sp = (const float*)src + (size_t)(k0 + k) * N + n0 + n;
      float4 f = *(const float4*)sp;
      v0 = f2b(f.x); v1 = f2b(f.y); v2 = f2b(f.z); v3 = f2b(f.w);
    } else {
      const short* sp = (const short*)src + (size_t)(k0 + k) * N + n0 + n;
      short4v s = *(const short4v*)sp;
      v0 = s[0]; v1 = s[1]; v2 = s[2]; v3 = s[3];
    }
    st[n + 0][k] = v0; st[n + 1][k] = v1; st[n + 2][k] = v2; st[n + 3][k] = v3;
  }
  __syncthreads();
  const int n = threadIdx.x >> 2;
  const int kc = (threadIdx.x & 3) << 4;
  short8 a = *(const short8*)(&st[n][kc]);
  short8 bb = *(const short8*)(&st[n][kc + 8]);
  short* dp = dst + (size_t)(n0 + n) * K + k0 + kc;
  *(short8*)(dp) = a;
  *(short8*)(dp + 8) = bb;
}

// ---------- OLD GEMM (fallback) ----------
__global__ __launch_bounds__(256, 2)
void gemm_bt(const void* __restrict__ A, int a_row0,
             const void* __restrict__ B, const void* __restrict__ bias,
             void* __restrict__ C, int c_row0, int N, int K,
             const int* __restrict__ dflag, int aIn, int cOut) {
  __shared__ short As[128 * 32];
  __shared__ short Bs[128 * 32];
  const bool f32 = (*dflag != 0);
  const bool a32 = aIn && f32;
  const bool c32 = cOut && f32;
  const int tid = threadIdx.x;
  const int lane = tid & 63, w = tid >> 6;
  const int wm = w & 1, wn = w >> 1;
  const int qg = lane >> 4, l16 = lane & 15;
  const int m0 = blockIdx.y << 7, n0 = blockIdx.x << 7;

  const int arow = tid >> 2, ak = (tid & 3) << 3;
  const int brow = tid >> 4, bc = (tid & 15) << 3;
  const int rot = tid & 15;

  floatx4 acc[4][4];
#pragma unroll
  for (int i = 0; i < 4; ++i)
#pragma unroll
    for (int j = 0; j < 4; ++j) acc[i][j] = (floatx4){0.f, 0.f, 0.f, 0.f};

  for (int k0 = 0; k0 < K; k0 += 32) {
    __syncthreads();
#pragma unroll
    for (int j = 0; j < 2; ++j) {
      short8 av = load8(A, (size_t)(a_row0 + m0 + j * 64 + arow) * K + (k0 + ak), a32);
      *(short8*)(As + (j * 64 + arow) * 32 + ak) = av;
      int kr = j * 16 + brow;
      short8 bv = load8(B, (size_t)(k0 + kr) * N + (n0 + bc), f32);
      int kq = kr >> 3, kj = kr & 7;
#pragma unroll
      for (int s = 0; s < 8; ++s) {
        int u = (s + rot) & 7;
        int n = bc + u;
        Bs[(n << 5) + ((kq ^ (n & 3)) << 3) + kj] = bv[u];
      }
    }
    __syncthreads();
    short8 a[4];
#pragma unroll
    for (int mi = 0; mi < 4; ++mi)
      a[mi] = *(const short8*)(As + (wm * 64 + mi * 16 + l16) * 32 + qg * 8);
#pragma unroll
    for (int ni = 0; ni < 4; ++ni) {
      int n = wn * 64 + ni * 16 + l16;
      short8 b = *(const short8*)(Bs + (n << 5) + ((qg ^ (n & 3)) << 3));
#pragma unroll
      for (int mi = 0; mi < 4; ++mi)
        acc[mi][ni] = __builtin_amdgcn_mfma_f32_16x16x32_bf16(a[mi], b, acc[mi][ni], 0, 0, 0);
    }
  }
#pragma unroll
  for (int ni = 0; ni < 4; ++ni) {
    int col = n0 + wn * 64 + ni * 16 + l16;
    float bv = bias ? loadf(bias, col, f32) : 0.0f;
#pragma unroll
    for (int mi = 0; mi < 4; ++mi) {
      int row = m0 + wm * 64 + mi * 16 + qg * 4;
#pragma unroll
      for (int r = 0; r < 4; ++r) {
        size_t idx = (size_t)(c_row0 + row + r) * N + col;
        float val = acc[mi][ni][r] + bv;
        if (c32) ((float*)C)[idx] = val;
        else     ((short*)C)[idx] = f2b(val);
      }
    }
  }
}

// ---------- GEMM v11 (qkv): 256x128 block tile, 128x64 wave tile, depth-2
// pipeline, single barrier/K-step, counted vmcnt(6), coalesced epilogue.
// (R22 lesson: do NOT fuse norm/rope here — the extra live state on top of
// acc[8][4]=128 f32 regs spills to scratch: VGPR 100->128, WRITE 46->197 MB,
// dur +130us. Epilogue fusions need O(few regs) added state.)
__global__ __launch_bounds__(256, 2)
void gemm_bf2(const short* __restrict__ A,
              const short* __restrict__ BTa, const void* __restrict__ biasa,
              int a0a, int c0a, int nYa,
              const short* __restrict__ BTb, const void* __restrict__ biasb,
              int a0b, int c0b,
              void* __restrict__ C, int N, int K,
              const int* __restrict__ dflag, int cOut) {
  __shared__ short Ls[3 * 8192 + 3 * 4096];    // 72 KB
#define ASB(b) (Ls + (b) * 8192)
#define BSB(b) (Ls + 24576 + (b) * 4096)
  const bool f32 = (*dflag != 0);
  const bool c32 = cOut && f32;
  const int bx = blockIdx.x;
  const int y = blockIdx.y;
  const short* BT; const void* bias; int arow0, crow0;
  if (y < nYa) { BT = BTa; bias = biasa; arow0 = a0a + (y << 8); crow0 = c0a + (y << 8); }
  else { int my = y - nYa; BT = BTb; bias = biasb; arow0 = a0b + (my << 8); crow0 = c0b + (my << 8); }
  const int tid = threadIdx.x;
  const int lane = tid & 63, w = tid >> 6;
  const int wm = w & 1, wn = w >> 1;
  const int qg = lane >> 4, l16 = lane & 15;
  const int n0 = bx << 7;
  const int garow = lane >> 2;
  const int gcir = lane & 3;
  const int nk = K >> 5;
  const int swz = (gcir ^ (garow & 3) ^ (garow >> 2)) << 3;
  const short* Abase = A + (size_t)(arow0 + w * 64 + garow) * K + swz;
  const short* Bbase = BT + (size_t)(n0 + w * 32 + garow) * K + swz;
  const int rswz = (l16 & 3) ^ (l16 >> 2);

  floatx4 acc[8][4];
#pragma unroll
  for (int i = 0; i < 8; ++i)
#pragma unroll
    for (int j = 0; j < 4; ++j) acc[i][j] = (floatx4){0.f, 0.f, 0.f, 0.f};

  auto STAGE = [&](int buf, int k0) {
#pragma unroll
    for (int j = 0; j < 4; ++j)
      gload16(Abase + (size_t)j * 16 * K + k0, ASB(buf) + ((w * 4 + j) << 9));
#pragma unroll
    for (int j = 0; j < 2; ++j)
      gload16(Bbase + (size_t)j * 16 * K + k0, BSB(buf) + ((w * 2 + j) << 9));
  };

  STAGE(0, 0);
  if (nk > 1) STAGE(1, 32);

  int cb = 0;
  for (int t = 0; t < nk; ++t) {
    if (t + 1 < nk) {
      asm volatile("s_waitcnt vmcnt(6) lgkmcnt(0)" ::: "memory");
    } else {
      asm volatile("s_waitcnt vmcnt(0) lgkmcnt(0)" ::: "memory");
    }
    __builtin_amdgcn_s_barrier();
    if (t + 2 < nk) {
      int sb = (cb == 0) ? 2 : cb - 1;
      STAGE(sb, (t + 2) << 5);
    }
    short8 a[8], b[4];
#pragma unroll
    for (int mi = 0; mi < 8; ++mi) {
      int ra = wm * 128 + mi * 16 + l16;
      a[mi] = *(const short8*)(ASB(cb) + (ra << 5) + ((qg ^ rswz) << 3));
    }
#pragma unroll
    for (int ni = 0; ni < 4; ++ni) {
      int n = wn * 64 + ni * 16 + l16;
      b[ni] = *(const short8*)(BSB(cb) + (n << 5) + ((qg ^ rswz) << 3));
    }
    __builtin_amdgcn_s_setprio(1);
#pragma unroll
    for (int ni = 0; ni < 4; ++ni)
#pragma unroll
      for (int mi = 0; mi < 8; ++mi)
        acc[mi][ni] = __builtin_amdgcn_mfma_f32_16x16x32_bf16(a[mi], b[ni], acc[mi][ni], 0, 0, 0);
    __builtin_amdgcn_s_setprio(0);
    cb = (cb == 2) ? 0 : cb + 1;
  }
  __builtin_amdgcn_s_barrier();
  if (!c32) {
    short* wreg = Ls + w * 4096;
#pragma unroll
    for (int half = 0; half < 2; ++half) {
#pragma unroll
      for (int ni = 0; ni < 4; ++ni) {
        float bvv = bias ? loadf(bias, n0 + wn * 64 + ni * 16 + l16, f32) : 0.0f;
#pragma unroll
        for (int mi2 = 0; mi2 < 4; ++mi2)
#pragma unroll
          for (int r = 0; r < 4; ++r)
            wreg[(mi2 * 16 + qg * 4 + r) * 64 + ni * 16 + l16] =
                f2b(acc[half * 4 + mi2][ni][r] + bvv);
      }
      asm volatile("s_waitcnt lgkmcnt(0)" ::: "memory");
#pragma unroll
      for (int j = 0; j < 8; ++j) {
        int row = j * 8 + (lane >> 3);
        int col = (lane & 7) * 8;
        short8 v = *(const short8*)(wreg + row * 64 + col);
        *(short8*)((short*)C + (size_t)(crow0 + wm * 128 + half * 64 + row) * N +
                   n0 + wn * 64 + col) = v;
      }
      asm volatile("s_waitcnt lgkmcnt(0)" ::: "memory");
    }
  } else {
    float* wregf = (float*)(Ls) + w * 2048;
#pragma unroll
    for (int half = 0; half < 2; ++half) {
#pragma unroll
      for (int ch = 0; ch < 2; ++ch) {
#pragma unroll
        for (int nh = 0; nh < 2; ++nh) {
          int ni = ch * 2 + nh;
          float bvv = bias ? loadf(bias, n0 + wn * 64 + ni * 16 + l16, f32) : 0.0f;
#pragma unroll
          for (int mi2 = 0; mi2 < 4; ++mi2)
#pragma unroll
            for (int r = 0; r < 4; ++r)
              wregf[(mi2 * 16 + qg * 4 + r) * 32 + nh * 16 + l16] =
                  acc[half * 4 + mi2][ni][r] + bvv;
        }
        asm volatile("s_waitcnt lgkmcnt(0)" ::: "memory");
#pragma unroll
        for (int j = 0; j < 8; ++j) {
          int row = j * 8 + (lane >> 3);
          int c4 = (lane & 7) * 4;
          float4 v = *(const float4*)(wregf + row * 32 + c4);
          *(float4*)((float*)C + (size_t)(crow0 + wm * 128 + half * 64 + row) * N +
                     n0 + wn * 64 + ch * 32 + c4) = v;
        }
        asm volatile("s_waitcnt lgkmcnt(0)" ::: "memory");
      }
    }
  }
#undef ASB
#undef BSB
}

// ---------- GEMM v10 variant (out-proj): 128x128 tile, 3 blocks/CU.
__global__ __launch_bounds__(256, 3)
void gemm_bf128(const short* __restrict__ A,
                const short* __restrict__ BTa, const void* __restrict__ biasa,
                int a0a, int c0a, int nYa,
                const short* __restrict__ BTb, const void* __restrict__ biasb,
                int a0b, int c0b,
                void* __restrict__ C, int N, int K,
                const int* __restrict__ dflag, int cOut) {
  __shared__ short Ls[6 * 128 * 32];           // 48 KB
#define ASB(b) (Ls + (b) * 4096)
#define BSB(b) (Ls + (3 + (b)) * 4096)
  const bool f32 = (*dflag != 0);
  const bool c32 = cOut && f32;
  const int bx = blockIdx.x;
  const int y = blockIdx.y;
  const short* BT; const void* bias; int arow0, crow0;
  if (y < nYa) { BT = BTa; bias = biasa; arow0 = a0a + (y << 7); crow0 = c0a + (y << 7); }
  else { int my = y - nYa; BT = BTb; bias = biasb; arow0 = a0b + (my << 7); crow0 = c0b + (my << 7); }
  const int tid = threadIdx.x;
  const int lane = tid & 63, w = tid >> 6;
  const int wm = w & 1, wn = w >> 1;
  const int qg = lane >> 4, l16 = lane & 15;
  const int n0 = bx << 7;
  const int garow = lane >> 2;
  const int gcir = lane & 3;
  const int nk = K >> 5;
  const int swz = (gcir ^ (garow & 3) ^ (garow >> 2)) << 3;
  const short* Abase = A + (size_t)(arow0 + w * 32 + garow) * K + swz;
  const short* Bbase = BT + (size_t)(n0 + w * 32 + garow) * K + swz;
  const int rswz = (l16 & 3) ^ (l16 >> 2);

  floatx4 acc[4][4];
#pragma unroll
  for (int i = 0; i < 4; ++i)
#pragma unroll
    for (int j = 0; j < 4; ++j) acc[i][j] = (floatx4){0.f, 0.f, 0.f, 0.f};

  auto STAGE = [&](int buf, int k0) {
#pragma unroll
    for (int j = 0; j < 2; ++j) {
      gload16(Abase + (size_t)j * 16 * K + k0, ASB(buf) + ((w * 2 + j) << 9));
      gload16(Bbase + (size_t)j * 16 * K + k0, BSB(buf) + ((w * 2 + j) << 9));
    }
  };

  STAGE(0, 0);
  if (nk > 1) STAGE(1, 32);

  int cb = 0;
  for (int t = 0; t < nk; ++t) {
    if (t + 1 < nk) {
      asm volatile("s_waitcnt vmcnt(4) lgkmcnt(0)" ::: "memory");
    } else {
      asm volatile("s_waitcnt vmcnt(0) lgkmcnt(0)" ::: "memory");
    }
    __builtin_amdgcn_s_barrier();
    if (t + 2 < nk) {
      int sb = (cb == 0) ? 2 : cb - 1;
      STAGE(sb, (t + 2) << 5);
    }
    short8 a[4], b[4];
#pragma unroll
    for (int mi = 0; mi < 4; ++mi) {
      int ra = wm * 64 + mi * 16 + l16;
      a[mi] = *(const short8*)(ASB(cb) + (ra << 5) + ((qg ^ rswz) << 3));
    }
#pragma unroll
    for (int ni = 0; ni < 4; ++ni) {
      int n = wn * 64 + ni * 16 + l16;
      b[ni] = *(const short8*)(BSB(cb) + (n << 5) + ((qg ^ rswz) << 3));
    }
    __builtin_amdgcn_s_setprio(1);
#pragma unroll
    for (int ni = 0; ni < 4; ++ni)
#pragma unroll
      for (int mi = 0; mi < 4; ++mi)
        acc[mi][ni] = __builtin_amdgcn_mfma_f32_16x16x32_bf16(a[mi], b[ni], acc[mi][ni], 0, 0, 0);
    __builtin_amdgcn_s_setprio(0);
    cb = (cb == 2) ? 0 : cb + 1;
  }
  __builtin_amdgcn_s_barrier();
  if (!c32) {
    short* wreg = Ls + w * 4096;
#pragma unroll
    for (int ni = 0; ni < 4; ++ni) {
      float bvv = bias ? loadf(bias, n0 + wn * 64 + ni * 16 + l16, f32) : 0.0f;
#pragma unroll
      for (int mi = 0; mi < 4; ++mi)
#pragma unroll
        for (int r = 0; r < 4; ++r)
          wreg[(mi * 16 + qg * 4 + r) * 64 + ni * 16 + l16] = f2b(acc[mi][ni][r] + bvv);
    }
    asm volatile("s_waitcnt lgkmcnt(0)" ::: "memory");
#pragma unroll
    for (int j = 0; j < 8; ++j) {
      int row = j * 8 + (lane >> 3);
      int col = (lane & 7) * 8;
      short8 v = *(const short8*)(wreg + row * 64 + col);
      *(short8*)((short*)C + (size_t)(crow0 + wm * 64 + row) * N + n0 + wn * 64 + col) = v;
    }
  } else {
    float* wregf = (float*)(Ls) + w * 2048;
#pragma unroll
    for (int half = 0; half < 2; ++half) {
#pragma unroll
      for (int nh = 0; nh < 2; ++nh) {
        int ni = half * 2 + nh;
        float bvv = bias ? loadf(bias, n0 + wn * 64 + ni * 16 + l16, f32) : 0.0f;
#pragma unroll
        for (int mi = 0; mi < 4; ++mi)
#pragma unroll
          for (int r = 0; r < 4; ++r)
            wregf[(mi * 16 + qg * 4 + r) * 32 + nh * 16 + l16] = acc[mi][ni][r] + bvv;
      }
      asm volatile("s_waitcnt lgkmcnt(0)" ::: "memory");
#pragma unroll
      for (int j = 0; j < 8; ++j) {
        int row = j * 8 + (lane >> 3);
        int c4 = (lane & 7) * 4;
        float4 v = *(const float4*)(wregf + row * 32 + c4);
        *(float4*)((float*)C + (size_t)(crow0 + wm * 64 + row) * N + n0 + wn * 64 + half * 32 + c4) = v;
      }
      asm volatile("s_waitcnt lgkmcnt(0)" ::: "memory");
    }
  }
#undef ASB
#undef BSB
}

// ---------- RMSNorm + RoPE: one wave per head; q scaled by rsqrt(128)*log2(e).
__global__ __launch_bounds__(512)
void norm_rope(short* __restrict__ qkv, const int* __restrict__ ids,
               const void* __restrict__ nqw, const void* __restrict__ nkw,
               const void* __restrict__ naqw, const void* __restrict__ nakw,
               const int* __restrict__ dflag) {
  const bool f32 = (*dflag != 0);
  const int t = blockIdx.x, wv = threadIdx.x >> 6, lane = threadIdx.x & 63;
  const bool txt = t < 512;
  int p = lane, axis; float expo;
  if (p < 8)       { axis = 0; expo = (float)(2 * p) * (1.0f / 16.0f); }
  else if (p < 36) { axis = 1; expo = (float)(2 * (p - 8)) * (1.0f / 56.0f); }
  else             { axis = 2; expo = (float)(2 * (p - 36)) * (1.0f / 56.0f); }
  float freq = __expf(-expo * 9.210340371976184f);
  float ang = (float)ids[t * 3 + axis] * freq;
  float s, c; sincosf(ang, &s, &c);
  const void* qw = txt ? naqw : nqw;
  const void* kw = txt ? nakw : nkw;
  float w0q = loadf(qw, 2 * lane, f32), w1q = loadf(qw, 2 * lane + 1, f32);
  float w0k = loadf(kw, 2 * lane, f32), w1k = loadf(kw, 2 * lane + 1, f32);
  const float QS = 0.08838834764831845f * 1.4426950408889634f;
#pragma unroll
  for (int i = 0; i < 3; ++i) {
    int h = wv + 8 * i;
    short* qp = qkv + (size_t)t * 9216 + h * 128 + 2 * lane;
    short* kp = qp + 3072;
    union { unsigned u; short sh[2]; } qv, kv;
    qv.u = *(const unsigned*)qp;
    kv.u = *(const unsigned*)kp;
    float q0 = b2f(qv.sh[0]), q1 = b2f(qv.sh[1]);
    float k0 = b2f(kv.sh[0]), k1 = b2f(kv.sh[1]);
    float sq = q0 * q0 + q1 * q1, sk = k0 * k0 + k1 * k1;
#pragma unroll
    for (int o = 1; o < 64; o <<= 1) { sq += __shfl_xor(sq, o); sk += __shfl_xor(sk, o); }
    float rq = rsqrtf(sq * (1.0f / 128.0f) + 1e-5f);
    float rk = rsqrtf(sk * (1.0f / 128.0f) + 1e-5f);
    float qn0 = q0 * rq * w0q, qn1 = q1 * rq * w1q;
    float kn0 = k0 * rk * w0k, kn1 = k1 * rk * w1k;
    float qo0 = qn0 * c - qn1 * s, qo1 = qn1 * c + qn0 * s;
    float ko0 = kn0 * c - kn1 * s, ko1 = kn1 * c + kn0 * s;
    union { unsigned u; short sh[2]; } qo, ko;
    qo.sh[0] = f2b(qo0 * QS);
    qo.sh[1] = f2b(qo1 * QS);
    ko.sh[0] = f2b(ko0); ko.sh[1] = f2b(ko1);
    *(unsigned*)qp = qo.u;
    *(unsigned*)kp = ko.u;
  }
}

// ---------- flash attention v10 (measured-best: Q128/KB128, 2 blocks/CU,
// Pw pitch-32 + XOR).
__global__ __launch_bounds__(512, 2)
void attn_fa(const short* __restrict__ qkv, short* __restrict__ attn) {
  __shared__ short KVs[2][128 * 128];   // 64 KB: K tiles; V^T overwrites in place
  __shared__ short Pw[8][512];          // 8 KB: per-wave P chunk (16 rows x 32 keys)
  const int wgid = blockIdx.x;
  const int xcd = wgid & 7, slot = wgid >> 3;   // 60 slots/XCD
  const int h = xcd * 3 + slot / 20;            // 3 heads per XCD (L2-resident K/V)
  const int qt = slot % 20;
  const int tid = threadIdx.x, lane = tid & 63, w = tid >> 6;  // 8 waves
  const int qg = lane >> 4, l16 = lane & 15;
  const int lr = lane >> 4, lc = lane & 15;
  const int q0 = qt << 7;
  const int sc = tid & 15;
  const int srow5 = (tid >> 4) & 15, half = tid >> 8;

  const short* Qg  = qkv + (size_t)q0 * 9216 + h * 128;
  const short* Kg0 = qkv + 3072 + h * 128;
  const short* Vg0 = qkv + 6144 + h * 128;

  // ---- prologue: K(0) gloads FIRST (drained by vmcnt(8)), then Q regs, V regs
#pragma unroll
  for (int j = 0; j < 4; ++j) {
    int row = j * 32 + w * 4 + lr;
    gload16(Kg0 + (size_t)row * 9216 + ((lc ^ (row & 7)) << 3),
            &KVs[0][(j * 32 + w * 4) * 128]);
  }
  short8 aq[4];
#pragma unroll
  for (int kc = 0; kc < 4; ++kc)
    aq[kc] = *(const short8*)(Qg + (size_t)(w * 16 + l16) * 9216 + kc * 32 + qg * 8);
  short8 vr[4];
#pragma unroll
  for (int j = 0; j < 4; ++j) {
    int row = half * 64 + j * 16 + srow5;
    vr[j] = *(const short8*)(Vg0 + (size_t)row * 9216 + sc * 8);
  }
  asm volatile("s_waitcnt vmcnt(8) lgkmcnt(0)" ::: "memory");  // K(0) done; Q,V in flight
  __builtin_amdgcn_s_barrier();

  floatx4 acc_o[8];
#pragma unroll
  for (int nd = 0; nd < 8; ++nd) acc_o[nd] = (floatx4){0.f, 0.f, 0.f, 0.f};
  float m_i[4], l_i[4];
#pragma unroll
  for (int r = 0; r < 4; ++r) { m_i[r] = -1e30f; l_i[r] = 0.0f; }

  for (int kt = 0; kt < 20; ++kt) {
    const int cb = kt & 1;
    asm volatile("s_waitcnt vmcnt(4) lgkmcnt(0)" ::: "memory");  // K(kt) landed; V(kt) in flight
    __builtin_amdgcn_s_barrier();
    if (kt < 19) {
      const short* Kg = qkv + ((size_t)(kt + 1) * 128) * 9216 + 3072 + h * 128;
#pragma unroll
      for (int j = 0; j < 4; ++j) {
        int row = j * 32 + w * 4 + lr;
        gload16(Kg + (size_t)row * 9216 + ((lc ^ (row & 7)) << 3),
                &KVs[1 - cb][(j * 32 + w * 4) * 128]);
      }
    }
    // ---- QK^T: 16 q-rows x 128 keys (scores in log2 domain via q-scale)
    floatx4 acc_s[8];
#pragma unroll
    for (int ni = 0; ni < 8; ++ni) acc_s[ni] = (floatx4){0.f, 0.f, 0.f, 0.f};
    __builtin_amdgcn_s_setprio(1);
#pragma unroll
    for (int kc = 0; kc < 4; ++kc) {
#pragma unroll
      for (int ni = 0; ni < 8; ++ni) {
        int row = ni * 16 + l16;
        short8 b = *(const short8*)(&KVs[cb][row * 128 + (((kc * 4 + qg) ^ (row & 7)) << 3)]);
        acc_s[ni] = __builtin_amdgcn_mfma_f32_16x16x32_bf16(aq[kc], b, acc_s[ni], 0, 0, 0);
      }
    }
    __builtin_amdgcn_s_setprio(0);
    // ---- online softmax, exp2 domain, defer-rescale (T13)
    float mxv[4];
    bool need = false;
#pragma unroll
    for (int r = 0; r < 4; ++r) {
      float mx = acc_s[0][r];
#pragma unroll
      for (int ni = 1; ni < 8; ++ni) mx = fmaxf(mx, acc_s[ni][r]);
      mx = fmaxf(mx, __shfl_xor(mx, 1));
      mx = fmaxf(mx, __shfl_xor(mx, 2));
      mx = fmaxf(mx, __shfl_xor(mx, 4));
      mx = fmaxf(mx, __shfl_xor(mx, 8));
      mxv[r] = mx;
      need = need || (mx > m_i[r] + 8.0f);
    }
    if (__ballot(need)) {
#pragma unroll
      for (int r = 0; r < 4; ++r) {
        float mn = fmaxf(m_i[r], mxv[r]);
        float al = __builtin_amdgcn_exp2f(m_i[r] - mn);
        m_i[r] = mn;
        l_i[r] *= al;
#pragma unroll
        for (int nd = 0; nd < 8; ++nd) acc_o[nd][r] *= al;
      }
    }
    // pkr[r][kc]: bf16x2 of (pv[2kc], pv[2kc+1]) — P chunk kc, in-chunk t'=2*l16(+1)
    unsigned pkr[4][4];
#pragma unroll
    for (int r = 0; r < 4; ++r) {
      float pv[8];
      float rs = 0.f;
#pragma unroll
      for (int ni = 0; ni < 8; ++ni) {
        pv[ni] = __builtin_amdgcn_exp2f(acc_s[ni][r] - m_i[r]);
        rs += pv[ni];
      }
#pragma unroll
      for (int kc = 0; kc < 4; ++kc) pkr[r][kc] = cvtpk(pv[2 * kc], pv[2 * kc + 1]);
      rs += __shfl_xor(rs, 1); rs += __shfl_xor(rs, 2);
      rs += __shfl_xor(rs, 4); rs += __shfl_xor(rs, 8);
      l_i[r] += rs;
    }
    asm volatile("s_waitcnt lgkmcnt(0)" ::: "memory");
    __builtin_amdgcn_s_barrier();   // QK^T reads of KVs[cb] done
    // ---- commit V^T(kt) into KVs[cb]: token r -> chunk r>>5, in-chunk
    // t' = 2*(r&15) + ((r>>4)&1).
#pragma unroll
    for (int u = 0; u < 8; ++u) {
      int d = sc * 8 + u;
      int xr = (d & 7) ^ ((d >> 3) & 7);
#pragma unroll
      for (int jp = 0; jp < 2; ++jp) {
        int kcw = 2 * half + jp;
        int g = kcw * 4 + (srow5 >> 2);
        union { unsigned uu; short sh[2]; } pk;
        pk.sh[0] = vr[2 * jp][u]; pk.sh[1] = vr[2 * jp + 1][u];
        *(unsigned*)(&KVs[cb][d * 128 + ((g ^ xr) << 3) + ((2 * srow5) & 7)]) = pk.uu;
      }
    }
    if (kt < 19) {
      const short* Vg = qkv + ((size_t)(kt + 1) * 128) * 9216 + 6144 + h * 128;
#pragma unroll
      for (int j = 0; j < 4; ++j) {
        int row = half * 64 + j * 16 + srow5;
        vr[j] = *(const short8*)(Vg + (size_t)row * 9216 + sc * 8);
      }
    }
    asm volatile("s_waitcnt lgkmcnt(0)" ::: "memory");
    __builtin_amdgcn_s_barrier();
    // ---- PV: per kc spill P chunk to wave-private Pw, read A-frag, 8 MFMA.
    __builtin_amdgcn_s_setprio(1);
#pragma unroll
    for (int kc = 0; kc < 4; ++kc) {
#pragma unroll
      for (int r = 0; r < 4; ++r)
        *(unsigned*)(&Pw[w][(qg * 4 + r) * 32 + ((l16 ^ (qg << 2)) << 1)]) = pkr[r][kc];
      short8 ap = *(const short8*)(&Pw[w][l16 * 32 + ((qg ^ (l16 >> 2)) << 3)]);
#pragma unroll
      for (int nd = 0; nd < 8; ++nd) {
        int d = nd * 16 + l16;
        int chn = (kc * 4 + qg) ^ (d & 7) ^ ((d >> 3) & 7);
        short8 b = *(const short8*)(&KVs[cb][d * 128 + (chn << 3)]);
        acc_o[nd] = __builtin_amdgcn_mfma_f32_16x16x32_bf16(ap, b, acc_o[nd], 0, 0, 0);
      }
    }
    __builtin_amdgcn_s_setprio(0);
  }
  // ---- epilogue: normalize, transpose through KVs (freed), coalesced stores
  asm volatile("s_waitcnt lgkmcnt(0)" ::: "memory");
  __builtin_amdgcn_s_barrier();   // all PV reads done
  short* Es = &KVs[0][0];         // 128 rows x 128 shorts
  float inv[4];
#pragma unroll
  for (int r = 0; r < 4; ++r) inv[r] = 1.0f / l_i[r];
#pragma unroll
  for (int nd = 0; nd < 8; ++nd)
#pragma unroll
    for (int r = 0; r < 4; ++r) {
      int row = w * 16 + qg * 4 + r;
      Es[row * 128 + nd * 16 + l16] = f2b(acc_o[nd][r] * inv[r]);
    }
  asm volatile("s_waitcnt lgkmcnt(0)" ::: "memory");   // wave-private rows
#pragma unroll
  for (int j = 0; j < 4; ++j) {
    int rrow = w * 16 + j * 4 + qg;
    short8 vv = *(const short8*)(Es + rrow * 128 + l16 * 8);
    *(short8*)(attn + (size_t)(q0 + rrow) * 3072 + h * 128 + l16 * 8) = vv;
  }
}

extern "C" void kernel_launch(void* const* d_in, const int* in_sizes, int n_in,
                              void* d_out, int out_size, void* d_ws, size_t ws_size,
                              hipStream_t stream) {
  (void)in_sizes; (void)n_in; (void)out_size;
  const void* hidden    = d_in[0];
  const void* enc       = d_in[1];
  const int*  ids       = (const int*)d_in[2];
  const void* w_qkv     = d_in[3];
  const void* w_add_qkv = d_in[4];
  const void* b_add_qkv = d_in[5];
  const void* w_out     = d_in[6];
  const void* b_out     = d_in[7];
  const void* w_add_out = d_in[8];
  const void* b_add_out = d_in[9];
  const void* nqw  = d_in[10];
  const void* nkw  = d_in[11];
  const void* naqw = d_in[12];
  const void* nakw = d_in[13];

  int*   dflag = (int*)d_ws;
  short* qkv   = (short*)((char*)d_ws + 256);   // [2560][9216] bf16
  short* attnB = qkv + (size_t)2560 * 9216;     // [2560][3072] bf16

  short* pool  = attnB + (size_t)2560 * 3072;
  const long n_hid  = 2048L * 3072;
  const long n_enc  = 512L * 3072;
  const long n_wqkv = 3072L * 9216;
  const long n_wout = 3072L * 3072;
  short* xb   = pool;                    // [2560][3072]
  short* wqb  = xb + n_enc + n_hid;      // w_qkv^T    [9216][3072]
  short* waqb = wqb + n_wqkv;            // w_add_qkv^T[9216][3072]
  short* wob  = waqb + n_wqkv;           // w_out^T    [3072][3072]
  short* waob = wob + n_wout;            // w_add_out^T[3072][3072]
  const size_t REQ = 256 + 2 * ((size_t)2560 * 9216 + (size_t)2560 * 3072 +
                                n_hid + n_enc + 2 * n_wqkv + 2 * n_wout);

  detect_dtype<<<1, 256, 0, stream>>>((const unsigned short*)w_qkv, dflag);

  if (ws_size >= REQ) {
    cvt_bf16_2<<<1024, 256, 0, stream>>>(enc, n_enc / 8, hidden, n_hid / 8, xb, dflag);
    cvt_tw<<<dim3(18432), 256, 0, stream>>>(w_qkv, wqb, w_add_qkv, waqb,
                                            w_out, wob, w_add_out, waob, dflag);

    // merged QKV projection, 256-row tiles: y<2 -> enc (bias), y>=2 -> hidden
    gemm_bf2<<<dim3(72, 10), 256, 0, stream>>>(
        xb, waqb, b_add_qkv, 0, 0, 2, wqb, nullptr, 512, 512,
        qkv, 9216, 3072, dflag, 0);
    norm_rope<<<dim3(2560), 512, 0, stream>>>(qkv, ids, nqw, nkw, naqw, nakw, dflag);
    // attention: 480 blocks = 24 heads x 20 q-tiles of 128, 2 blocks/CU
    attn_fa<<<dim3(480), 512, 0, stream>>>(qkv, attnB);
    // merged out-proj, 128-row tiles: y<16 img, y>=16 enc
    gemm_bf128<<<dim3(24, 20), 256, 0, stream>>>(
        attnB, wob, b_out, 512, 0, 16, waob, b_add_out, 0, 2048,
        d_out, 3072, 3072, dflag, 1);
  } else {
    gemm_bt<<<dim3(72, 4), 256, 0, stream>>>(enc, 0, w_add_qkv, b_add_qkv, qkv, 0, 9216, 3072, dflag, 1, 0);
    gemm_bt<<<dim3(72, 16), 256, 0, stream>>>(hidden, 0, w_qkv, nullptr, qkv, 512, 9216, 3072, dflag, 1, 0);
    norm_rope<<<dim3(2560), 512, 0, stream>>>(qkv, ids, nqw, nkw, naqw, nakw, dflag);
    attn_fa<<<dim3(480), 512, 0, stream>>>(qkv, attnB);
    gemm_bt<<<dim3(24, 16), 256, 0, stream>>>(attnB, 512, w_out, b_out, d_out, 0, 3072, 3072, dflag, 0, 1);
    gemm_bt<<<dim3(24, 4), 256, 0, stream>>>(attnB, 0, w_add_out, b_add_out, d_out, 2048, 3072, 3072, dflag, 0, 1);
  }
}

// Round 24
// 783.880 us; speedup vs baseline: 1.1624x; 1.0009x over previous
//
#include <hip/hip_runtime.h>

typedef __attribute__((ext_vector_type(8))) short short8;
typedef __attribute__((ext_vector_type(4))) short short4v;
typedef __attribute__((ext_vector_type(4))) float floatx4;

__device__ __forceinline__ float b2f(short b) {
  union { unsigned u; float f; } v; v.u = ((unsigned)(unsigned short)b) << 16; return v.f;
}
__device__ __forceinline__ short f2b(float f) {
  union { float f; unsigned u; } v; v.f = f;
  return (short)((v.u + 0x7fffu + ((v.u >> 16) & 1u)) >> 16);
}
// packed f32x2 -> bf16x2 (RNE), single VOP3 instr
__device__ __forceinline__ unsigned cvtpk(float lo, float hi) {
  unsigned r;
  asm("v_cvt_pk_bf16_f32 %0, %1, %2" : "=v"(r) : "v"(lo), "v"(hi));
  return r;
}
__device__ __forceinline__ float loadf(const void* p, size_t i, bool f32) {
  return f32 ? ((const float*)p)[i] : b2f(((const short*)p)[i]);
}
__device__ __forceinline__ short8 load8(const void* p, size_t i, bool f32) {
  if (f32) {
    const float* fp = (const float*)p + i;
    float4 a = *(const float4*)fp;
    float4 b = *(const float4*)(fp + 4);
    short8 r;
    r[0] = f2b(a.x); r[1] = f2b(a.y); r[2] = f2b(a.z); r[3] = f2b(a.w);
    r[4] = f2b(b.x); r[5] = f2b(b.y); r[6] = f2b(b.z); r[7] = f2b(b.w);
    return r;
  }
  return *(const short8*)((const short*)p + i);
}

// async global->LDS, 16B per lane. LDS dest = wave-uniform base + lane*16.
__device__ __forceinline__ void gload16(const short* g, short* l) {
  __builtin_amdgcn_global_load_lds(
      (const __attribute__((address_space(1))) unsigned int*)g,
      (__attribute__((address_space(3))) unsigned int*)l, 16, 0, 0);
}

// ---------- dtype detector
__global__ void detect_dtype(const unsigned short* __restrict__ w, int* __restrict__ flag) {
  __shared__ int cnt;
  if (threadIdx.x == 0) cnt = 0;
  __syncthreads();
  int bad = 0;
  for (int i = threadIdx.x; i < 4096; i += 256) {
    int e = (w[i] >> 7) & 0xFF;
    if (e >= 0xC8) bad++;
  }
  atomicAdd(&cnt, bad);
  __syncthreads();
  if (threadIdx.x == 0) *flag = (cnt > 64) ? 1 : 0;
}

// ---------- one-time dtype normalization: two sources -> one contiguous dst
__global__ __launch_bounds__(256)
void cvt_bf16_2(const void* __restrict__ srcA, long n8A,
                const void* __restrict__ srcB, long n8B,
                short* __restrict__ dst, const int* __restrict__ dflag) {
  const bool f32 = (*dflag != 0);
  const long n8 = n8A + n8B;
  long stride = (long)gridDim.x * 256;
  for (long i = (long)blockIdx.x * 256 + threadIdx.x; i < n8; i += stride) {
    const void* s; long e;
    if (i < n8A) { s = srcA; e = i * 8; } else { s = srcB; e = (i - n8A) * 8; }
    if (f32) {
      const float* fp = (const float*)s + e;
      float4 a = *(const float4*)fp;
      float4 b = *(const float4*)(fp + 4);
      short8 r;
      r[0] = f2b(a.x); r[1] = f2b(a.y); r[2] = f2b(a.z); r[3] = f2b(a.w);
      r[4] = f2b(b.x); r[5] = f2b(b.y); r[6] = f2b(b.z); r[7] = f2b(b.w);
      *(short8*)(dst + i * 8) = r;
    } else {
      *(short8*)(dst + i * 8) = *(const short8*)((const short*)s + e);
    }
  }
}

// ---------- cvt_tw: all 4 weight transposes in ONE launch (1-D grid decode).
__global__ __launch_bounds__(256)
void cvt_tw(const void* __restrict__ wq, short* __restrict__ wqd,
            const void* __restrict__ waq, short* __restrict__ waqd,
            const void* __restrict__ wo, short* __restrict__ wod,
            const void* __restrict__ wao, short* __restrict__ waod,
            const int* __restrict__ dflag) {
  __shared__ short st[64][72];
  const bool f32 = (*dflag != 0);
  const int K = 3072;
  int b = blockIdx.x;
  const void* src; short* dst; int N, n0, k0;
  if (b < 13824) {
    src = (b < 6912) ? wq : waq;
    dst = (b < 6912) ? wqd : waqd;
    int rem = b % 6912;
    N = 9216; n0 = (rem % 144) << 6; k0 = (rem / 144) << 6;
  } else {
    b -= 13824;
    src = (b < 2304) ? wo : wao;
    dst = (b < 2304) ? wod : waod;
    int rem = b % 2304;
    N = 3072; n0 = (rem % 48) << 6; k0 = (rem / 48) << 6;
  }
  const int c4 = threadIdx.x & 15;
  const int rq = threadIdx.x >> 4;
#pragma unroll
  for (int r = 0; r < 4; ++r) {
    int k = r * 16 + rq;
    int n = c4 * 4;
    short v0, v1, v2, v3;
    if (f32) {
      const float* sp = (const float*)src + (size_t)(k0 + k) * N + n0 + n;
      float4 f = *(const float4*)sp;
      v0 = f2b(f.x); v1 = f2b(f.y); v2 = f2b(f.z); v3 = f2b(f.w);
    } else {
      const short* sp = (const short*)src + (size_t)(k0 + k) * N + n0 + n;
      short4v s = *(const short4v*)sp;
      v0 = s[0]; v1 = s[1]; v2 = s[2]; v3 = s[3];
    }
    st[n + 0][k] = v0; st[n + 1][k] = v1; st[n + 2][k] = v2; st[n + 3][k] = v3;
  }
  __syncthreads();
  const int n = threadIdx.x >> 2;
  const int kc = (threadIdx.x & 3) << 4;
  short8 a = *(const short8*)(&st[n][kc]);
  short8 bb = *(const short8*)(&st[n][kc + 8]);
  short* dp = dst + (size_t)(n0 + n) * K + k0 + kc;
  *(short8*)(dp) = a;
  *(short8*)(dp + 8) = bb;
}

// ---------- OLD GEMM (fallback) ----------
__global__ __launch_bounds__(256, 2)
void gemm_bt(const void* __restrict__ A, int a_row0,
             const void* __restrict__ B, const void* __restrict__ bias,
             void* __restrict__ C, int c_row0, int N, int K,
             const int* __restrict__ dflag, int aIn, int cOut) {
  __shared__ short As[128 * 32];
  __shared__ short Bs[128 * 32];
  const bool f32 = (*dflag != 0);
  const bool a32 = aIn && f32;
  const bool c32 = cOut && f32;
  const int tid = threadIdx.x;
  const int lane = tid & 63, w = tid >> 6;
  const int wm = w & 1, wn = w >> 1;
  const int qg = lane >> 4, l16 = lane & 15;
  const int m0 = blockIdx.y << 7, n0 = blockIdx.x << 7;

  const int arow = tid >> 2, ak = (tid & 3) << 3;
  const int brow = tid >> 4, bc = (tid & 15) << 3;
  const int rot = tid & 15;

  floatx4 acc[4][4];
#pragma unroll
  for (int i = 0; i < 4; ++i)
#pragma unroll
    for (int j = 0; j < 4; ++j) acc[i][j] = (floatx4){0.f, 0.f, 0.f, 0.f};

  for (int k0 = 0; k0 < K; k0 += 32) {
    __syncthreads();
#pragma unroll
    for (int j = 0; j < 2; ++j) {
      short8 av = load8(A, (size_t)(a_row0 + m0 + j * 64 + arow) * K + (k0 + ak), a32);
      *(short8*)(As + (j * 64 + arow) * 32 + ak) = av;
      int kr = j * 16 + brow;
      short8 bv = load8(B, (size_t)(k0 + kr) * N + (n0 + bc), f32);
      int kq = kr >> 3, kj = kr & 7;
#pragma unroll
      for (int s = 0; s < 8; ++s) {
        int u = (s + rot) & 7;
        int n = bc + u;
        Bs[(n << 5) + ((kq ^ (n & 3)) << 3) + kj] = bv[u];
      }
    }
    __syncthreads();
    short8 a[4];
#pragma unroll
    for (int mi = 0; mi < 4; ++mi)
      a[mi] = *(const short8*)(As + (wm * 64 + mi * 16 + l16) * 32 + qg * 8);
#pragma unroll
    for (int ni = 0; ni < 4; ++ni) {
      int n = wn * 64 + ni * 16 + l16;
      short8 b = *(const short8*)(Bs + (n << 5) + ((qg ^ (n & 3)) << 3));
#pragma unroll
      for (int mi = 0; mi < 4; ++mi)
        acc[mi][ni] = __builtin_amdgcn_mfma_f32_16x16x32_bf16(a[mi], b, acc[mi][ni], 0, 0, 0);
    }
  }
#pragma unroll
  for (int ni = 0; ni < 4; ++ni) {
    int col = n0 + wn * 64 + ni * 16 + l16;
    float bv = bias ? loadf(bias, col, f32) : 0.0f;
#pragma unroll
    for (int mi = 0; mi < 4; ++mi) {
      int row = m0 + wm * 64 + mi * 16 + qg * 4;
#pragma unroll
      for (int r = 0; r < 4; ++r) {
        size_t idx = (size_t)(c_row0 + row + r) * N + col;
        float val = acc[mi][ni][r] + bv;
        if (c32) ((float*)C)[idx] = val;
        else     ((short*)C)[idx] = f2b(val);
      }
    }
  }
}

// ---------- GEMM v11 (qkv): 256x128 block tile, 128x64 wave tile, depth-2
// pipeline, single barrier/K-step, counted vmcnt(6), coalesced epilogue.
__global__ __launch_bounds__(256, 2)
void gemm_bf2(const short* __restrict__ A,
              const short* __restrict__ BTa, const void* __restrict__ biasa,
              int a0a, int c0a, int nYa,
              const short* __restrict__ BTb, const void* __restrict__ biasb,
              int a0b, int c0b,
              void* __restrict__ C, int N, int K,
              const int* __restrict__ dflag, int cOut) {
  __shared__ short Ls[3 * 8192 + 3 * 4096];    // 72 KB
#define ASB(b) (Ls + (b) * 8192)
#define BSB(b) (Ls + 24576 + (b) * 4096)
  const bool f32 = (*dflag != 0);
  const bool c32 = cOut && f32;
  const int bx = blockIdx.x;
  const int y = blockIdx.y;
  const short* BT; const void* bias; int arow0, crow0;
  if (y < nYa) { BT = BTa; bias = biasa; arow0 = a0a + (y << 8); crow0 = c0a + (y << 8); }
  else { int my = y - nYa; BT = BTb; bias = biasb; arow0 = a0b + (my << 8); crow0 = c0b + (my << 8); }
  const int tid = threadIdx.x;
  const int lane = tid & 63, w = tid >> 6;
  const int wm = w & 1, wn = w >> 1;
  const int qg = lane >> 4, l16 = lane & 15;
  const int n0 = bx << 7;
  const int garow = lane >> 2;
  const int gcir = lane & 3;
  const int nk = K >> 5;
  const int swz = (gcir ^ (garow & 3) ^ (garow >> 2)) << 3;
  const short* Abase = A + (size_t)(arow0 + w * 64 + garow) * K + swz;
  const short* Bbase = BT + (size_t)(n0 + w * 32 + garow) * K + swz;
  const int rswz = (l16 & 3) ^ (l16 >> 2);

  floatx4 acc[8][4];
#pragma unroll
  for (int i = 0; i < 8; ++i)
#pragma unroll
    for (int j = 0; j < 4; ++j) acc[i][j] = (floatx4){0.f, 0.f, 0.f, 0.f};

  auto STAGE = [&](int buf, int k0) {
#pragma unroll
    for (int j = 0; j < 4; ++j)
      gload16(Abase + (size_t)j * 16 * K + k0, ASB(buf) + ((w * 4 + j) << 9));
#pragma unroll
    for (int j = 0; j < 2; ++j)
      gload16(Bbase + (size_t)j * 16 * K + k0, BSB(buf) + ((w * 2 + j) << 9));
  };

  STAGE(0, 0);
  if (nk > 1) STAGE(1, 32);

  int cb = 0;
  for (int t = 0; t < nk; ++t) {
    if (t + 1 < nk) {
      asm volatile("s_waitcnt vmcnt(6) lgkmcnt(0)" ::: "memory");
    } else {
      asm volatile("s_waitcnt vmcnt(0) lgkmcnt(0)" ::: "memory");
    }
    __builtin_amdgcn_s_barrier();
    if (t + 2 < nk) {
      int sb = (cb == 0) ? 2 : cb - 1;
      STAGE(sb, (t + 2) << 5);
    }
    short8 a[8], b[4];
#pragma unroll
    for (int mi = 0; mi < 8; ++mi) {
      int ra = wm * 128 + mi * 16 + l16;
      a[mi] = *(const short8*)(ASB(cb) + (ra << 5) + ((qg ^ rswz) << 3));
    }
#pragma unroll
    for (int ni = 0; ni < 4; ++ni) {
      int n = wn * 64 + ni * 16 + l16;
      b[ni] = *(const short8*)(BSB(cb) + (n << 5) + ((qg ^ rswz) << 3));
    }
    __builtin_amdgcn_s_setprio(1);
#pragma unroll
    for (int ni = 0; ni < 4; ++ni)
#pragma unroll
      for (int mi = 0; mi < 8; ++mi)
        acc[mi][ni] = __builtin_amdgcn_mfma_f32_16x16x32_bf16(a[mi], b[ni], acc[mi][ni], 0, 0, 0);
    __builtin_amdgcn_s_setprio(0);
    cb = (cb == 2) ? 0 : cb + 1;
  }
  __builtin_amdgcn_s_barrier();
  if (!c32) {
    short* wreg = Ls + w * 4096;
#pragma unroll
    for (int half = 0; half < 2; ++half) {
#pragma unroll
      for (int ni = 0; ni < 4; ++ni) {
        float bvv = bias ? loadf(bias, n0 + wn * 64 + ni * 16 + l16, f32) : 0.0f;
#pragma unroll
        for (int mi2 = 0; mi2 < 4; ++mi2)
#pragma unroll
          for (int r = 0; r < 4; ++r)
            wreg[(mi2 * 16 + qg * 4 + r) * 64 + ni * 16 + l16] =
                f2b(acc[half * 4 + mi2][ni][r] + bvv);
      }
      asm volatile("s_waitcnt lgkmcnt(0)" ::: "memory");
#pragma unroll
      for (int j = 0; j < 8; ++j) {
        int row = j * 8 + (lane >> 3);
        int col = (lane & 7) * 8;
        short8 v = *(const short8*)(wreg + row * 64 + col);
        *(short8*)((short*)C + (size_t)(crow0 + wm * 128 + half * 64 + row) * N +
                   n0 + wn * 64 + col) = v;
      }
      asm volatile("s_waitcnt lgkmcnt(0)" ::: "memory");
    }
  } else {
    float* wregf = (float*)(Ls) + w * 2048;
#pragma unroll
    for (int half = 0; half < 2; ++half) {
#pragma unroll
      for (int ch = 0; ch < 2; ++ch) {
#pragma unroll
        for (int nh = 0; nh < 2; ++nh) {
          int ni = ch * 2 + nh;
          float bvv = bias ? loadf(bias, n0 + wn * 64 + ni * 16 + l16, f32) : 0.0f;
#pragma unroll
          for (int mi2 = 0; mi2 < 4; ++mi2)
#pragma unroll
            for (int r = 0; r < 4; ++r)
              wregf[(mi2 * 16 + qg * 4 + r) * 32 + nh * 16 + l16] =
                  acc[half * 4 + mi2][ni][r] + bvv;
        }
        asm volatile("s_waitcnt lgkmcnt(0)" ::: "memory");
#pragma unroll
        for (int j = 0; j < 8; ++j) {
          int row = j * 8 + (lane >> 3);
          int c4 = (lane & 7) * 4;
          float4 v = *(const float4*)(wregf + row * 32 + c4);
          *(float4*)((float*)C + (size_t)(crow0 + wm * 128 + half * 64 + row) * N +
                     n0 + wn * 64 + ch * 32 + c4) = v;
        }
        asm volatile("s_waitcnt lgkmcnt(0)" ::: "memory");
      }
    }
  }
#undef ASB
#undef BSB
}

// ---------- GEMM v10 variant (out-proj): 128x128 tile, 3 blocks/CU.
__global__ __launch_bounds__(256, 3)
void gemm_bf128(const short* __restrict__ A,
                const short* __restrict__ BTa, const void* __restrict__ biasa,
                int a0a, int c0a, int nYa,
                const short* __restrict__ BTb, const void* __restrict__ biasb,
                int a0b, int c0b,
                void* __restrict__ C, int N, int K,
                const int* __restrict__ dflag, int cOut) {
  __shared__ short Ls[6 * 128 * 32];           // 48 KB
#define ASB(b) (Ls + (b) * 4096)
#define BSB(b) (Ls + (3 + (b)) * 4096)
  const bool f32 = (*dflag != 0);
  const bool c32 = cOut && f32;
  const int bx = blockIdx.x;
  const int y = blockIdx.y;
  const short* BT; const void* bias; int arow0, crow0;
  if (y < nYa) { BT = BTa; bias = biasa; arow0 = a0a + (y << 7); crow0 = c0a + (y << 7); }
  else { int my = y - nYa; BT = BTb; bias = biasb; arow0 = a0b + (my << 7); crow0 = c0b + (my << 7); }
  const int tid = threadIdx.x;
  const int lane = tid & 63, w = tid >> 6;
  const int wm = w & 1, wn = w >> 1;
  const int qg = lane >> 4, l16 = lane & 15;
  const int n0 = bx << 7;
  const int garow = lane >> 2;
  const int gcir = lane & 3;
  const int nk = K >> 5;
  const int swz = (gcir ^ (garow & 3) ^ (garow >> 2)) << 3;
  const short* Abase = A + (size_t)(arow0 + w * 32 + garow) * K + swz;
  const short* Bbase = BT + (size_t)(n0 + w * 32 + garow) * K + swz;
  const int rswz = (l16 & 3) ^ (l16 >> 2);

  floatx4 acc[4][4];
#pragma unroll
  for (int i = 0; i < 4; ++i)
#pragma unroll
    for (int j = 0; j < 4; ++j) acc[i][j] = (floatx4){0.f, 0.f, 0.f, 0.f};

  auto STAGE = [&](int buf, int k0) {
#pragma unroll
    for (int j = 0; j < 2; ++j) {
      gload16(Abase + (size_t)j * 16 * K + k0, ASB(buf) + ((w * 2 + j) << 9));
      gload16(Bbase + (size_t)j * 16 * K + k0, BSB(buf) + ((w * 2 + j) << 9));
    }
  };

  STAGE(0, 0);
  if (nk > 1) STAGE(1, 32);

  int cb = 0;
  for (int t = 0; t < nk; ++t) {
    if (t + 1 < nk) {
      asm volatile("s_waitcnt vmcnt(4) lgkmcnt(0)" ::: "memory");
    } else {
      asm volatile("s_waitcnt vmcnt(0) lgkmcnt(0)" ::: "memory");
    }
    __builtin_amdgcn_s_barrier();
    if (t + 2 < nk) {
      int sb = (cb == 0) ? 2 : cb - 1;
      STAGE(sb, (t + 2) << 5);
    }
    short8 a[4], b[4];
#pragma unroll
    for (int mi = 0; mi < 4; ++mi) {
      int ra = wm * 64 + mi * 16 + l16;
      a[mi] = *(const short8*)(ASB(cb) + (ra << 5) + ((qg ^ rswz) << 3));
    }
#pragma unroll
    for (int ni = 0; ni < 4; ++ni) {
      int n = wn * 64 + ni * 16 + l16;
      b[ni] = *(const short8*)(BSB(cb) + (n << 5) + ((qg ^ rswz) << 3));
    }
    __builtin_amdgcn_s_setprio(1);
#pragma unroll
    for (int ni = 0; ni < 4; ++ni)
#pragma unroll
      for (int mi = 0; mi < 4; ++mi)
        acc[mi][ni] = __builtin_amdgcn_mfma_f32_16x16x32_bf16(a[mi], b[ni], acc[mi][ni], 0, 0, 0);
    __builtin_amdgcn_s_setprio(0);
    cb = (cb == 2) ? 0 : cb + 1;
  }
  __builtin_amdgcn_s_barrier();
  if (!c32) {
    short* wreg = Ls + w * 4096;
#pragma unroll
    for (int ni = 0; ni < 4; ++ni) {
      float bvv = bias ? loadf(bias, n0 + wn * 64 + ni * 16 + l16, f32) : 0.0f;
#pragma unroll
      for (int mi = 0; mi < 4; ++mi)
#pragma unroll
        for (int r = 0; r < 4; ++r)
          wreg[(mi * 16 + qg * 4 + r) * 64 + ni * 16 + l16] = f2b(acc[mi][ni][r] + bvv);
    }
    asm volatile("s_waitcnt lgkmcnt(0)" ::: "memory");
#pragma unroll
    for (int j = 0; j < 8; ++j) {
      int row = j * 8 + (lane >> 3);
      int col = (lane & 7) * 8;
      short8 v = *(const short8*)(wreg + row * 64 + col);
      *(short8*)((short*)C + (size_t)(crow0 + wm * 64 + row) * N + n0 + wn * 64 + col) = v;
    }
  } else {
    float* wregf = (float*)(Ls) + w * 2048;
#pragma unroll
    for (int half = 0; half < 2; ++half) {
#pragma unroll
      for (int nh = 0; nh < 2; ++nh) {
        int ni = half * 2 + nh;
        float bvv = bias ? loadf(bias, n0 + wn * 64 + ni * 16 + l16, f32) : 0.0f;
#pragma unroll
        for (int mi = 0; mi < 4; ++mi)
#pragma unroll
          for (int r = 0; r < 4; ++r)
            wregf[(mi * 16 + qg * 4 + r) * 32 + nh * 16 + l16] = acc[mi][ni][r] + bvv;
      }
      asm volatile("s_waitcnt lgkmcnt(0)" ::: "memory");
#pragma unroll
      for (int j = 0; j < 8; ++j) {
        int row = j * 8 + (lane >> 3);
        int c4 = (lane & 7) * 4;
        float4 v = *(const float4*)(wregf + row * 32 + c4);
        *(float4*)((float*)C + (size_t)(crow0 + wm * 64 + row) * N + n0 + wn * 64 + half * 32 + c4) = v;
      }
      asm volatile("s_waitcnt lgkmcnt(0)" ::: "memory");
    }
  }
#undef ASB
#undef BSB
}

// ---------- RMSNorm + RoPE: one wave per head; q scaled by rsqrt(128)*log2(e).
__global__ __launch_bounds__(512)
void norm_rope(short* __restrict__ qkv, const int* __restrict__ ids,
               const void* __restrict__ nqw, const void* __restrict__ nkw,
               const void* __restrict__ naqw, const void* __restrict__ nakw,
               const int* __restrict__ dflag) {
  const bool f32 = (*dflag != 0);
  const int t = blockIdx.x, wv = threadIdx.x >> 6, lane = threadIdx.x & 63;
  const bool txt = t < 512;
  int p = lane, axis; float expo;
  if (p < 8)       { axis = 0; expo = (float)(2 * p) * (1.0f / 16.0f); }
  else if (p < 36) { axis = 1; expo = (float)(2 * (p - 8)) * (1.0f / 56.0f); }
  else             { axis = 2; expo = (float)(2 * (p - 36)) * (1.0f / 56.0f); }
  float freq = __expf(-expo * 9.210340371976184f);
  float ang = (float)ids[t * 3 + axis] * freq;
  float s, c; sincosf(ang, &s, &c);
  const void* qw = txt ? naqw : nqw;
  const void* kw = txt ? nakw : nkw;
  float w0q = loadf(qw, 2 * lane, f32), w1q = loadf(qw, 2 * lane + 1, f32);
  float w0k = loadf(kw, 2 * lane, f32), w1k = loadf(kw, 2 * lane + 1, f32);
  const float QS = 0.08838834764831845f * 1.4426950408889634f;
#pragma unroll
  for (int i = 0; i < 3; ++i) {
    int h = wv + 8 * i;
    short* qp = qkv + (size_t)t * 9216 + h * 128 + 2 * lane;
    short* kp = qp + 3072;
    union { unsigned u; short sh[2]; } qv, kv;
    qv.u = *(const unsigned*)qp;
    kv.u = *(const unsigned*)kp;
    float q0 = b2f(qv.sh[0]), q1 = b2f(qv.sh[1]);
    float k0 = b2f(kv.sh[0]), k1 = b2f(kv.sh[1]);
    float sq = q0 * q0 + q1 * q1, sk = k0 * k0 + k1 * k1;
#pragma unroll
    for (int o = 1; o < 64; o <<= 1) { sq += __shfl_xor(sq, o); sk += __shfl_xor(sk, o); }
    float rq = rsqrtf(sq * (1.0f / 128.0f) + 1e-5f);
    float rk = rsqrtf(sk * (1.0f / 128.0f) + 1e-5f);
    float qn0 = q0 * rq * w0q, qn1 = q1 * rq * w1q;
    float kn0 = k0 * rk * w0k, kn1 = k1 * rk * w1k;
    float qo0 = qn0 * c - qn1 * s, qo1 = qn1 * c + qn0 * s;
    float ko0 = kn0 * c - kn1 * s, ko1 = kn1 * c + kn0 * s;
    union { unsigned u; short sh[2]; } qo, ko;
    qo.sh[0] = f2b(qo0 * QS);
    qo.sh[1] = f2b(qo1 * QS);
    ko.sh[0] = f2b(ko0); ko.sh[1] = f2b(ko1);
    *(unsigned*)qp = qo.u;
    *(unsigned*)kp = ko.u;
  }
}

// ---------- flash attention v12 = v10 with conflict-free Pw banking.
// v10's Pw write (row qg*4+r, unit l16^4qg) had row parity = r&1 only ->
// all 64 lanes in one 16-bank half -> 4-way write. v12: physical row
// phi(x) = ((x&3)<<2)|(x>>2) (write rows 4r+qg: parity spreads over qg) and
// per-row group-xor X = (p>>1)&3. Both write AND read are 2-way (enumerated);
// read stays 16B-aligned b128 at pitch 32 (the R19 pitch-40 failure avoided).
// Logical P content identical to v10.
__global__ __launch_bounds__(512, 2)
void attn_fa(const short* __restrict__ qkv, short* __restrict__ attn) {
  __shared__ short KVs[2][128 * 128];   // 64 KB: K tiles; V^T overwrites in place
  __shared__ short Pw[8][512];          // 8 KB: per-wave P chunk (16 rows x 32 keys)
  const int wgid = blockIdx.x;
  const int xcd = wgid & 7, slot = wgid >> 3;   // 60 slots/XCD
  const int h = xcd * 3 + slot / 20;            // 3 heads per XCD (L2-resident K/V)
  const int qt = slot % 20;
  const int tid = threadIdx.x, lane = tid & 63, w = tid >> 6;  // 8 waves
  const int qg = lane >> 4, l16 = lane & 15;
  const int lr = lane >> 4, lc = lane & 15;
  const int q0 = qt << 7;
  const int sc = tid & 15;
  const int srow5 = (tid >> 4) & 15, half = tid >> 8;

  const short* Qg  = qkv + (size_t)q0 * 9216 + h * 128;
  const short* Kg0 = qkv + 3072 + h * 128;
  const short* Vg0 = qkv + 6144 + h * 128;

  // ---- prologue: K(0) gloads FIRST (drained by vmcnt(8)), then Q regs, V regs
#pragma unroll
  for (int j = 0; j < 4; ++j) {
    int row = j * 32 + w * 4 + lr;
    gload16(Kg0 + (size_t)row * 9216 + ((lc ^ (row & 7)) << 3),
            &KVs[0][(j * 32 + w * 4) * 128]);
  }
  short8 aq[4];
#pragma unroll
  for (int kc = 0; kc < 4; ++kc)
    aq[kc] = *(const short8*)(Qg + (size_t)(w * 16 + l16) * 9216 + kc * 32 + qg * 8);
  short8 vr[4];
#pragma unroll
  for (int j = 0; j < 4; ++j) {
    int row = half * 64 + j * 16 + srow5;
    vr[j] = *(const short8*)(Vg0 + (size_t)row * 9216 + sc * 8);
  }
  asm volatile("s_waitcnt vmcnt(8) lgkmcnt(0)" ::: "memory");  // K(0) done; Q,V in flight
  __builtin_amdgcn_s_barrier();

  floatx4 acc_o[8];
#pragma unroll
  for (int nd = 0; nd < 8; ++nd) acc_o[nd] = (floatx4){0.f, 0.f, 0.f, 0.f};
  float m_i[4], l_i[4];
#pragma unroll
  for (int r = 0; r < 4; ++r) { m_i[r] = -1e30f; l_i[r] = 0.0f; }

  // Pw addressing (see header comment): write phys row pw_r = 4r+qg, read
  // phys row pr = 4*(l16&3) + (l16>>2); both with group-xor (p>>1)&3.
  const int pr = 4 * (l16 & 3) + (l16 >> 2);            // phi(l16)
  const int prx = (pr >> 1) & 3;
  const int rdoff = pr * 32 + ((qg ^ prx) << 3);        // read base (shorts)

  for (int kt = 0; kt < 20; ++kt) {
    const int cb = kt & 1;
    asm volatile("s_waitcnt vmcnt(4) lgkmcnt(0)" ::: "memory");  // K(kt) landed; V(kt) in flight
    __builtin_amdgcn_s_barrier();
    if (kt < 19) {
      const short* Kg = qkv + ((size_t)(kt + 1) * 128) * 9216 + 3072 + h * 128;
#pragma unroll
      for (int j = 0; j < 4; ++j) {
        int row = j * 32 + w * 4 + lr;
        gload16(Kg + (size_t)row * 9216 + ((lc ^ (row & 7)) << 3),
                &KVs[1 - cb][(j * 32 + w * 4) * 128]);
      }
    }
    // ---- QK^T: 16 q-rows x 128 keys (scores in log2 domain via q-scale)
    floatx4 acc_s[8];
#pragma unroll
    for (int ni = 0; ni < 8; ++ni) acc_s[ni] = (floatx4){0.f, 0.f, 0.f, 0.f};
    __builtin_amdgcn_s_setprio(1);
#pragma unroll
    for (int kc = 0; kc < 4; ++kc) {
#pragma unroll
      for (int ni = 0; ni < 8; ++ni) {
        int row = ni * 16 + l16;
        short8 b = *(const short8*)(&KVs[cb][row * 128 + (((kc * 4 + qg) ^ (row & 7)) << 3)]);
        acc_s[ni] = __builtin_amdgcn_mfma_f32_16x16x32_bf16(aq[kc], b, acc_s[ni], 0, 0, 0);
      }
    }
    __builtin_amdgcn_s_setprio(0);
    // ---- online softmax, exp2 domain, defer-rescale (T13)
    float mxv[4];
    bool need = false;
#pragma unroll
    for (int r = 0; r < 4; ++r) {
      float mx = acc_s[0][r];
#pragma unroll
      for (int ni = 1; ni < 8; ++ni) mx = fmaxf(mx, acc_s[ni][r]);
      mx = fmaxf(mx, __shfl_xor(mx, 1));
      mx = fmaxf(mx, __shfl_xor(mx, 2));
      mx = fmaxf(mx, __shfl_xor(mx, 4));
      mx = fmaxf(mx, __shfl_xor(mx, 8));
      mxv[r] = mx;
      need = need || (mx > m_i[r] + 8.0f);
    }
    if (__ballot(need)) {
#pragma unroll
      for (int r = 0; r < 4; ++r) {
        float mn = fmaxf(m_i[r], mxv[r]);
        float al = __builtin_amdgcn_exp2f(m_i[r] - mn);
        m_i[r] = mn;
        l_i[r] *= al;
#pragma unroll
        for (int nd = 0; nd < 8; ++nd) acc_o[nd][r] *= al;
      }
    }
    // pkr[r][kc]: bf16x2 of (pv[2kc], pv[2kc+1]) — P chunk kc, in-chunk t'=2*l16(+1)
    unsigned pkr[4][4];
#pragma unroll
    for (int r = 0; r < 4; ++r) {
      float pv[8];
      float rs = 0.f;
#pragma unroll
      for (int ni = 0; ni < 8; ++ni) {
        pv[ni] = __builtin_amdgcn_exp2f(acc_s[ni][r] - m_i[r]);
        rs += pv[ni];
      }
#pragma unroll
      for (int kc = 0; kc < 4; ++kc) pkr[r][kc] = cvtpk(pv[2 * kc], pv[2 * kc + 1]);
      rs += __shfl_xor(rs, 1); rs += __shfl_xor(rs, 2);
      rs += __shfl_xor(rs, 4); rs += __shfl_xor(rs, 8);
      l_i[r] += rs;
    }
    asm volatile("s_waitcnt lgkmcnt(0)" ::: "memory");
    __builtin_amdgcn_s_barrier();   // QK^T reads of KVs[cb] done
    // ---- commit V^T(kt) into KVs[cb]: token r -> chunk r>>5, in-chunk
    // t' = 2*(r&15) + ((r>>4)&1).
#pragma unroll
    for (int u = 0; u < 8; ++u) {
      int d = sc * 8 + u;
      int xr = (d & 7) ^ ((d >> 3) & 7);
#pragma unroll
      for (int jp = 0; jp < 2; ++jp) {
        int kcw = 2 * half + jp;
        int g = kcw * 4 + (srow5 >> 2);
        union { unsigned uu; short sh[2]; } pk;
        pk.sh[0] = vr[2 * jp][u]; pk.sh[1] = vr[2 * jp + 1][u];
        *(unsigned*)(&KVs[cb][d * 128 + ((g ^ xr) << 3) + ((2 * srow5) & 7)]) = pk.uu;
      }
    }
    if (kt < 19) {
      const short* Vg = qkv + ((size_t)(kt + 1) * 128) * 9216 + 6144 + h * 128;
#pragma unroll
      for (int j = 0; j < 4; ++j) {
        int row = half * 64 + j * 16 + srow5;
        vr[j] = *(const short8*)(Vg + (size_t)row * 9216 + sc * 8);
      }
    }
    asm volatile("s_waitcnt lgkmcnt(0)" ::: "memory");
    __builtin_amdgcn_s_barrier();
    // ---- PV: per kc spill P chunk to wave-private Pw, read A-frag, 8 MFMA.
    __builtin_amdgcn_s_setprio(1);
#pragma unroll
    for (int kc = 0; kc < 4; ++kc) {
#pragma unroll
      for (int r = 0; r < 4; ++r) {
        int pw = 4 * r + qg;               // phi(qg*4+r)
        int pwx = (pw >> 1) & 3;
        *(unsigned*)(&Pw[w][pw * 32 + ((l16 & 3) << 1) + (((l16 >> 2) ^ pwx) << 3)]) = pkr[r][kc];
      }
      short8 ap = *(const short8*)(&Pw[w][rdoff]);
#pragma unroll
      for (int nd = 0; nd < 8; ++nd) {
        int d = nd * 16 + l16;
        int chn = (kc * 4 + qg) ^ (d & 7) ^ ((d >> 3) & 7);
        short8 b = *(const short8*)(&KVs[cb][d * 128 + (chn << 3)]);
        acc_o[nd] = __builtin_amdgcn_mfma_f32_16x16x32_bf16(ap, b, acc_o[nd], 0, 0, 0);
      }
    }
    __builtin_amdgcn_s_setprio(0);
  }
  // ---- epilogue: normalize, transpose through KVs (freed), coalesced stores
  asm volatile("s_waitcnt lgkmcnt(0)" ::: "memory");
  __builtin_amdgcn_s_barrier();   // all PV reads done
  short* Es = &KVs[0][0];         // 128 rows x 128 shorts
  float inv[4];
#pragma unroll
  for (int r = 0; r < 4; ++r) inv[r] = 1.0f / l_i[r];
#pragma unroll
  for (int nd = 0; nd < 8; ++nd)
#pragma unroll
    for (int r = 0; r < 4; ++r) {
      int row = w * 16 + qg * 4 + r;
      Es[row * 128 + nd * 16 + l16] = f2b(acc_o[nd][r] * inv[r]);
    }
  asm volatile("s_waitcnt lgkmcnt(0)" ::: "memory");   // wave-private rows
#pragma unroll
  for (int j = 0; j < 4; ++j) {
    int rrow = w * 16 + j * 4 + qg;
    short8 vv = *(const short8*)(Es + rrow * 128 + l16 * 8);
    *(short8*)(attn + (size_t)(q0 + rrow) * 3072 + h * 128 + l16 * 8) = vv;
  }
}

extern "C" void kernel_launch(void* const* d_in, const int* in_sizes, int n_in,
                              void* d_out, int out_size, void* d_ws, size_t ws_size,
                              hipStream_t stream) {
  (void)in_sizes; (void)n_in; (void)out_size;
  const void* hidden    = d_in[0];
  const void* enc       = d_in[1];
  const int*  ids       = (const int*)d_in[2];
  const void* w_qkv     = d_in[3];
  const void* w_add_qkv = d_in[4];
  const void* b_add_qkv = d_in[5];
  const void* w_out     = d_in[6];
  const void* b_out     = d_in[7];
  const void* w_add_out = d_in[8];
  const void* b_add_out = d_in[9];
  const void* nqw  = d_in[10];
  const void* nkw  = d_in[11];
  const void* naqw = d_in[12];
  const void* nakw = d_in[13];

  int*   dflag = (int*)d_ws;
  short* qkv   = (short*)((char*)d_ws + 256);   // [2560][9216] bf16
  short* attnB = qkv + (size_t)2560 * 9216;     // [2560][3072] bf16

  short* pool  = attnB + (size_t)2560 * 3072;
  const long n_hid  = 2048L * 3072;
  const long n_enc  = 512L * 3072;
  const long n_wqkv = 3072L * 9216;
  const long n_wout = 3072L * 3072;
  short* xb   = pool;                    // [2560][3072]
  short* wqb  = xb + n_enc + n_hid;      // w_qkv^T    [9216][3072]
  short* waqb = wqb + n_wqkv;            // w_add_qkv^T[9216][3072]
  short* wob  = waqb + n_wqkv;           // w_out^T    [3072][3072]
  short* waob = wob + n_wout;            // w_add_out^T[3072][3072]
  const size_t REQ = 256 + 2 * ((size_t)2560 * 9216 + (size_t)2560 * 3072 +
                                n_hid + n_enc + 2 * n_wqkv + 2 * n_wout);

  detect_dtype<<<1, 256, 0, stream>>>((const unsigned short*)w_qkv, dflag);

  if (ws_size >= REQ) {
    cvt_bf16_2<<<1024, 256, 0, stream>>>(enc, n_enc / 8, hidden, n_hid / 8, xb, dflag);
    cvt_tw<<<dim3(18432), 256, 0, stream>>>(w_qkv, wqb, w_add_qkv, waqb,
                                            w_out, wob, w_add_out, waob, dflag);

    // merged QKV projection, 256-row tiles: y<2 -> enc (bias), y>=2 -> hidden
    gemm_bf2<<<dim3(72, 10), 256, 0, stream>>>(
        xb, waqb, b_add_qkv, 0, 0, 2, wqb, nullptr, 512, 512,
        qkv, 9216, 3072, dflag, 0);
    norm_rope<<<dim3(2560), 512, 0, stream>>>(qkv, ids, nqw, nkw, naqw, nakw, dflag);
    // attention: 480 blocks = 24 heads x 20 q-tiles of 128, 2 blocks/CU
    attn_fa<<<dim3(480), 512, 0, stream>>>(qkv, attnB);
    // merged out-proj, 128-row tiles: y<16 img, y>=16 enc
    gemm_bf128<<<dim3(24, 20), 256, 0, stream>>>(
        attnB, wob, b_out, 512, 0, 16, waob, b_add_out, 0, 2048,
        d_out, 3072, 3072, dflag, 1);
  } else {
    gemm_bt<<<dim3(72, 4), 256, 0, stream>>>(enc, 0, w_add_qkv, b_add_qkv, qkv, 0, 9216, 3072, dflag, 1, 0);
    gemm_bt<<<dim3(72, 16), 256, 0, stream>>>(hidden, 0, w_qkv, nullptr, qkv, 512, 9216, 3072, dflag, 1, 0);
    norm_rope<<<dim3(2560), 512, 0, stream>>>(qkv, ids, nqw, nkw, naqw, nakw, dflag);
    attn_fa<<<dim3(480), 512, 0, stream>>>(qkv, attnB);
    gemm_bt<<<dim3(24, 16), 256, 0, stream>>>(attnB, 512, w_out, b_out, d_out, 0, 3072, 3072, dflag, 0, 1);
    gemm_bt<<<dim3(24, 4), 256, 0, stream>>>(attnB, 0, w_add_out, b_add_out, d_out, 2048, 3072, 3072, dflag, 0, 1);
  }
}

// Round 25
// 768.126 us; speedup vs baseline: 1.1863x; 1.0205x over previous
//
#include <hip/hip_runtime.h>

typedef __attribute__((ext_vector_type(8))) short short8;
typedef __attribute__((ext_vector_type(4))) short short4v;
typedef __attribute__((ext_vector_type(4))) float floatx4;

__device__ __forceinline__ float b2f(short b) {
  union { unsigned u; float f; } v; v.u = ((unsigned)(unsigned short)b) << 16; return v.f;
}
__device__ __forceinline__ short f2b(float f) {
  union { float f; unsigned u; } v; v.f = f;
  return (short)((v.u + 0x7fffu + ((v.u >> 16) & 1u)) >> 16);
}
// packed f32x2 -> bf16x2 (RNE), single VOP3 instr
__device__ __forceinline__ unsigned cvtpk(float lo, float hi) {
  unsigned r;
  asm("v_cvt_pk_bf16_f32 %0, %1, %2" : "=v"(r) : "v"(lo), "v"(hi));
  return r;
}
__device__ __forceinline__ float loadf(const void* p, size_t i, bool f32) {
  return f32 ? ((const float*)p)[i] : b2f(((const short*)p)[i]);
}
__device__ __forceinline__ short8 load8(const void* p, size_t i, bool f32) {
  if (f32) {
    const float* fp = (const float*)p + i;
    float4 a = *(const float4*)fp;
    float4 b = *(const float4*)(fp + 4);
    short8 r;
    r[0] = f2b(a.x); r[1] = f2b(a.y); r[2] = f2b(a.z); r[3] = f2b(a.w);
    r[4] = f2b(b.x); r[5] = f2b(b.y); r[6] = f2b(b.z); r[7] = f2b(b.w);
    return r;
  }
  return *(const short8*)((const short*)p + i);
}

// async global->LDS, 16B per lane. LDS dest = wave-uniform base + lane*16.
__device__ __forceinline__ void gload16(const short* g, short* l) {
  __builtin_amdgcn_global_load_lds(
      (const __attribute__((address_space(1))) unsigned int*)g,
      (__attribute__((address_space(3))) unsigned int*)l, 16, 0, 0);
}

// ---------- dtype detector
__global__ void detect_dtype(const unsigned short* __restrict__ w, int* __restrict__ flag) {
  __shared__ int cnt;
  if (threadIdx.x == 0) cnt = 0;
  __syncthreads();
  int bad = 0;
  for (int i = threadIdx.x; i < 4096; i += 256) {
    int e = (w[i] >> 7) & 0xFF;
    if (e >= 0xC8) bad++;
  }
  atomicAdd(&cnt, bad);
  __syncthreads();
  if (threadIdx.x == 0) *flag = (cnt > 64) ? 1 : 0;
}

// ---------- cvt_all: 4 weight transposes + activation copy in ONE launch.
// b < 13824: qkv-weight transpose; b < 18432: out-weight transpose;
// b >= 18432 (1024 blocks): enc+hidden -> xb grid-stride copy/convert.
// Copy branch is block-uniform and touches neither LDS nor barriers.
__global__ __launch_bounds__(256)
void cvt_all(const void* __restrict__ wq, short* __restrict__ wqd,
             const void* __restrict__ waq, short* __restrict__ waqd,
             const void* __restrict__ wo, short* __restrict__ wod,
             const void* __restrict__ wao, short* __restrict__ waod,
             const void* __restrict__ srcA, long n8A,
             const void* __restrict__ srcB, long n8B,
             short* __restrict__ dstX,
             const int* __restrict__ dflag) {
  const bool f32 = (*dflag != 0);
  int b = blockIdx.x;
  if (b >= 18432) {                      // ---- activation copy branch
    const long n8 = n8A + n8B;
    const long stride = 1024L * 256;
    for (long i = (long)(b - 18432) * 256 + threadIdx.x; i < n8; i += stride) {
      const void* s; long e;
      if (i < n8A) { s = srcA; e = i * 8; } else { s = srcB; e = (i - n8A) * 8; }
      if (f32) {
        const float* fp = (const float*)s + e;
        float4 a = *(const float4*)fp;
        float4 bb = *(const float4*)(fp + 4);
        short8 r;
        r[0] = f2b(a.x); r[1] = f2b(a.y); r[2] = f2b(a.z); r[3] = f2b(a.w);
        r[4] = f2b(bb.x); r[5] = f2b(bb.y); r[6] = f2b(bb.z); r[7] = f2b(bb.w);
        *(short8*)(dstX + i * 8) = r;
      } else {
        *(short8*)(dstX + i * 8) = *(const short8*)((const short*)s + e);
      }
    }
    return;
  }
  // ---- weight transpose branch (identical to cvt_tw)
  __shared__ short st[64][72];
  const int K = 3072;
  const void* src; short* dst; int N, n0, k0;
  if (b < 13824) {
    src = (b < 6912) ? wq : waq;
    dst = (b < 6912) ? wqd : waqd;
    int rem = b % 6912;
    N = 9216; n0 = (rem % 144) << 6; k0 = (rem / 144) << 6;
  } else {
    b -= 13824;
    src = (b < 2304) ? wo : wao;
    dst = (b < 2304) ? wod : waod;
    int rem = b % 2304;
    N = 3072; n0 = (rem % 48) << 6; k0 = (rem / 48) << 6;
  }
  const int c4 = threadIdx.x & 15;
  const int rq = threadIdx.x >> 4;
#pragma unroll
  for (int r = 0; r < 4; ++r) {
    int k = r * 16 + rq;
    int n = c4 * 4;
    short v0, v1, v2, v3;
    if (f32) {
      const float* sp = (const float*)src + (size_t)(k0 + k) * N + n0 + n;
      float4 f = *(const float4*)sp;
      v0 = f2b(f.x); v1 = f2b(f.y); v2 = f2b(f.z); v3 = f2b(f.w);
    } else {
      const short* sp = (const short*)src + (size_t)(k0 + k) * N + n0 + n;
      short4v s = *(const short4v*)sp;
      v0 = s[0]; v1 = s[1]; v2 = s[2]; v3 = s[3];
    }
    st[n + 0][k] = v0; st[n + 1][k] = v1; st[n + 2][k] = v2; st[n + 3][k] = v3;
  }
  __syncthreads();
  const int n = threadIdx.x >> 2;
  const int kc = (threadIdx.x & 3) << 4;
  short8 a = *(const short8*)(&st[n][kc]);
  short8 bb = *(const short8*)(&st[n][kc + 8]);
  short* dp = dst + (size_t)(n0 + n) * K + k0 + kc;
  *(short8*)(dp) = a;
  *(short8*)(dp + 8) = bb;
}

// ---------- OLD GEMM (fallback) ----------
__global__ __launch_bounds__(256, 2)
void gemm_bt(const void* __restrict__ A, int a_row0,
             const void* __restrict__ B, const void* __restrict__ bias,
             void* __restrict__ C, int c_row0, int N, int K,
             const int* __restrict__ dflag, int aIn, int cOut) {
  __shared__ short As[128 * 32];
  __shared__ short Bs[128 * 32];
  const bool f32 = (*dflag != 0);
  const bool a32 = aIn && f32;
  const bool c32 = cOut && f32;
  const int tid = threadIdx.x;
  const int lane = tid & 63, w = tid >> 6;
  const int wm = w & 1, wn = w >> 1;
  const int qg = lane >> 4, l16 = lane & 15;
  const int m0 = blockIdx.y << 7, n0 = blockIdx.x << 7;

  const int arow = tid >> 2, ak = (tid & 3) << 3;
  const int brow = tid >> 4, bc = (tid & 15) << 3;
  const int rot = tid & 15;

  floatx4 acc[4][4];
#pragma unroll
  for (int i = 0; i < 4; ++i)
#pragma unroll
    for (int j = 0; j < 4; ++j) acc[i][j] = (floatx4){0.f, 0.f, 0.f, 0.f};

  for (int k0 = 0; k0 < K; k0 += 32) {
    __syncthreads();
#pragma unroll
    for (int j = 0; j < 2; ++j) {
      short8 av = load8(A, (size_t)(a_row0 + m0 + j * 64 + arow) * K + (k0 + ak), a32);
      *(short8*)(As + (j * 64 + arow) * 32 + ak) = av;
      int kr = j * 16 + brow;
      short8 bv = load8(B, (size_t)(k0 + kr) * N + (n0 + bc), f32);
      int kq = kr >> 3, kj = kr & 7;
#pragma unroll
      for (int s = 0; s < 8; ++s) {
        int u = (s + rot) & 7;
        int n = bc + u;
        Bs[(n << 5) + ((kq ^ (n & 3)) << 3) + kj] = bv[u];
      }
    }
    __syncthreads();
    short8 a[4];
#pragma unroll
    for (int mi = 0; mi < 4; ++mi)
      a[mi] = *(const short8*)(As + (wm * 64 + mi * 16 + l16) * 32 + qg * 8);
#pragma unroll
    for (int ni = 0; ni < 4; ++ni) {
      int n = wn * 64 + ni * 16 + l16;
      short8 b = *(const short8*)(Bs + (n << 5) + ((qg ^ (n & 3)) << 3));
#pragma unroll
      for (int mi = 0; mi < 4; ++mi)
        acc[mi][ni] = __builtin_amdgcn_mfma_f32_16x16x32_bf16(a[mi], b, acc[mi][ni], 0, 0, 0);
    }
  }
#pragma unroll
  for (int ni = 0; ni < 4; ++ni) {
    int col = n0 + wn * 64 + ni * 16 + l16;
    float bv = bias ? loadf(bias, col, f32) : 0.0f;
#pragma unroll
    for (int mi = 0; mi < 4; ++mi) {
      int row = m0 + wm * 64 + mi * 16 + qg * 4;
#pragma unroll
      for (int r = 0; r < 4; ++r) {
        size_t idx = (size_t)(c_row0 + row + r) * N + col;
        float val = acc[mi][ni][r] + bv;
        if (c32) ((float*)C)[idx] = val;
        else     ((short*)C)[idx] = f2b(val);
      }
    }
  }
}

// ---------- GEMM v11 (qkv): 256x128 block tile, 128x64 wave tile, depth-2
// pipeline, single barrier/K-step, counted vmcnt(6), coalesced epilogue.
__global__ __launch_bounds__(256, 2)
void gemm_bf2(const short* __restrict__ A,
              const short* __restrict__ BTa, const void* __restrict__ biasa,
              int a0a, int c0a, int nYa,
              const short* __restrict__ BTb, const void* __restrict__ biasb,
              int a0b, int c0b,
              void* __restrict__ C, int N, int K,
              const int* __restrict__ dflag, int cOut) {
  __shared__ short Ls[3 * 8192 + 3 * 4096];    // 72 KB
#define ASB(b) (Ls + (b) * 8192)
#define BSB(b) (Ls + 24576 + (b) * 4096)
  const bool f32 = (*dflag != 0);
  const bool c32 = cOut && f32;
  const int bx = blockIdx.x;
  const int y = blockIdx.y;
  const short* BT; const void* bias; int arow0, crow0;
  if (y < nYa) { BT = BTa; bias = biasa; arow0 = a0a + (y << 8); crow0 = c0a + (y << 8); }
  else { int my = y - nYa; BT = BTb; bias = biasb; arow0 = a0b + (my << 8); crow0 = c0b + (my << 8); }
  const int tid = threadIdx.x;
  const int lane = tid & 63, w = tid >> 6;
  const int wm = w & 1, wn = w >> 1;
  const int qg = lane >> 4, l16 = lane & 15;
  const int n0 = bx << 7;
  const int garow = lane >> 2;
  const int gcir = lane & 3;
  const int nk = K >> 5;
  const int swz = (gcir ^ (garow & 3) ^ (garow >> 2)) << 3;
  const short* Abase = A + (size_t)(arow0 + w * 64 + garow) * K + swz;
  const short* Bbase = BT + (size_t)(n0 + w * 32 + garow) * K + swz;
  const int rswz = (l16 & 3) ^ (l16 >> 2);

  floatx4 acc[8][4];
#pragma unroll
  for (int i = 0; i < 8; ++i)
#pragma unroll
    for (int j = 0; j < 4; ++j) acc[i][j] = (floatx4){0.f, 0.f, 0.f, 0.f};

  auto STAGE = [&](int buf, int k0) {
#pragma unroll
    for (int j = 0; j < 4; ++j)
      gload16(Abase + (size_t)j * 16 * K + k0, ASB(buf) + ((w * 4 + j) << 9));
#pragma unroll
    for (int j = 0; j < 2; ++j)
      gload16(Bbase + (size_t)j * 16 * K + k0, BSB(buf) + ((w * 2 + j) << 9));
  };

  STAGE(0, 0);
  if (nk > 1) STAGE(1, 32);

  int cb = 0;
  for (int t = 0; t < nk; ++t) {
    if (t + 1 < nk) {
      asm volatile("s_waitcnt vmcnt(6) lgkmcnt(0)" ::: "memory");
    } else {
      asm volatile("s_waitcnt vmcnt(0) lgkmcnt(0)" ::: "memory");
    }
    __builtin_amdgcn_s_barrier();
    if (t + 2 < nk) {
      int sb = (cb == 0) ? 2 : cb - 1;
      STAGE(sb, (t + 2) << 5);
    }
    short8 a[8], b[4];
#pragma unroll
    for (int mi = 0; mi < 8; ++mi) {
      int ra = wm * 128 + mi * 16 + l16;
      a[mi] = *(const short8*)(ASB(cb) + (ra << 5) + ((qg ^ rswz) << 3));
    }
#pragma unroll
    for (int ni = 0; ni < 4; ++ni) {
      int n = wn * 64 + ni * 16 + l16;
      b[ni] = *(const short8*)(BSB(cb) + (n << 5) + ((qg ^ rswz) << 3));
    }
    __builtin_amdgcn_s_setprio(1);
#pragma unroll
    for (int ni = 0; ni < 4; ++ni)
#pragma unroll
      for (int mi = 0; mi < 8; ++mi)
        acc[mi][ni] = __builtin_amdgcn_mfma_f32_16x16x32_bf16(a[mi], b[ni], acc[mi][ni], 0, 0, 0);
    __builtin_amdgcn_s_setprio(0);
    cb = (cb == 2) ? 0 : cb + 1;
  }
  __builtin_amdgcn_s_barrier();
  if (!c32) {
    short* wreg = Ls + w * 4096;
#pragma unroll
    for (int half = 0; half < 2; ++half) {
#pragma unroll
      for (int ni = 0; ni < 4; ++ni) {
        float bvv = bias ? loadf(bias, n0 + wn * 64 + ni * 16 + l16, f32) : 0.0f;
#pragma unroll
        for (int mi2 = 0; mi2 < 4; ++mi2)
#pragma unroll
          for (int r = 0; r < 4; ++r)
            wreg[(mi2 * 16 + qg * 4 + r) * 64 + ni * 16 + l16] =
                f2b(acc[half * 4 + mi2][ni][r] + bvv);
      }
      asm volatile("s_waitcnt lgkmcnt(0)" ::: "memory");
#pragma unroll
      for (int j = 0; j < 8; ++j) {
        int row = j * 8 + (lane >> 3);
        int col = (lane & 7) * 8;
        short8 v = *(const short8*)(wreg + row * 64 + col);
        *(short8*)((short*)C + (size_t)(crow0 + wm * 128 + half * 64 + row) * N +
                   n0 + wn * 64 + col) = v;
      }
      asm volatile("s_waitcnt lgkmcnt(0)" ::: "memory");
    }
  } else {
    float* wregf = (float*)(Ls) + w * 2048;
#pragma unroll
    for (int half = 0; half < 2; ++half) {
#pragma unroll
      for (int ch = 0; ch < 2; ++ch) {
#pragma unroll
        for (int nh = 0; nh < 2; ++nh) {
          int ni = ch * 2 + nh;
          float bvv = bias ? loadf(bias, n0 + wn * 64 + ni * 16 + l16, f32) : 0.0f;
#pragma unroll
          for (int mi2 = 0; mi2 < 4; ++mi2)
#pragma unroll
            for (int r = 0; r < 4; ++r)
              wregf[(mi2 * 16 + qg * 4 + r) * 32 + nh * 16 + l16] =
                  acc[half * 4 + mi2][ni][r] + bvv;
        }
        asm volatile("s_waitcnt lgkmcnt(0)" ::: "memory");
#pragma unroll
        for (int j = 0; j < 8; ++j) {
          int row = j * 8 + (lane >> 3);
          int c4 = (lane & 7) * 4;
          float4 v = *(const float4*)(wregf + row * 32 + c4);
          *(float4*)((float*)C + (size_t)(crow0 + wm * 128 + half * 64 + row) * N +
                     n0 + wn * 64 + ch * 32 + c4) = v;
        }
        asm volatile("s_waitcnt lgkmcnt(0)" ::: "memory");
      }
    }
  }
#undef ASB
#undef BSB
}

// ---------- GEMM v10 variant (out-proj): 128x128 tile, 3 blocks/CU.
__global__ __launch_bounds__(256, 3)
void gemm_bf128(const short* __restrict__ A,
                const short* __restrict__ BTa, const void* __restrict__ biasa,
                int a0a, int c0a, int nYa,
                const short* __restrict__ BTb, const void* __restrict__ biasb,
                int a0b, int c0b,
                void* __restrict__ C, int N, int K,
                const int* __restrict__ dflag, int cOut) {
  __shared__ short Ls[6 * 128 * 32];           // 48 KB
#define ASB(b) (Ls + (b) * 4096)
#define BSB(b) (Ls + (3 + (b)) * 4096)
  const bool f32 = (*dflag != 0);
  const bool c32 = cOut && f32;
  const int bx = blockIdx.x;
  const int y = blockIdx.y;
  const short* BT; const void* bias; int arow0, crow0;
  if (y < nYa) { BT = BTa; bias = biasa; arow0 = a0a + (y << 7); crow0 = c0a + (y << 7); }
  else { int my = y - nYa; BT = BTb; bias = biasb; arow0 = a0b + (my << 7); crow0 = c0b + (my << 7); }
  const int tid = threadIdx.x;
  const int lane = tid & 63, w = tid >> 6;
  const int wm = w & 1, wn = w >> 1;
  const int qg = lane >> 4, l16 = lane & 15;
  const int n0 = bx << 7;
  const int garow = lane >> 2;
  const int gcir = lane & 3;
  const int nk = K >> 5;
  const int swz = (gcir ^ (garow & 3) ^ (garow >> 2)) << 3;
  const short* Abase = A + (size_t)(arow0 + w * 32 + garow) * K + swz;
  const short* Bbase = BT + (size_t)(n0 + w * 32 + garow) * K + swz;
  const int rswz = (l16 & 3) ^ (l16 >> 2);

  floatx4 acc[4][4];
#pragma unroll
  for (int i = 0; i < 4; ++i)
#pragma unroll
    for (int j = 0; j < 4; ++j) acc[i][j] = (floatx4){0.f, 0.f, 0.f, 0.f};

  auto STAGE = [&](int buf, int k0) {
#pragma unroll
    for (int j = 0; j < 2; ++j) {
      gload16(Abase + (size_t)j * 16 * K + k0, ASB(buf) + ((w * 2 + j) << 9));
      gload16(Bbase + (size_t)j * 16 * K + k0, BSB(buf) + ((w * 2 + j) << 9));
    }
  };

  STAGE(0, 0);
  if (nk > 1) STAGE(1, 32);

  int cb = 0;
  for (int t = 0; t < nk; ++t) {
    if (t + 1 < nk) {
      asm volatile("s_waitcnt vmcnt(4) lgkmcnt(0)" ::: "memory");
    } else {
      asm volatile("s_waitcnt vmcnt(0) lgkmcnt(0)" ::: "memory");
    }
    __builtin_amdgcn_s_barrier();
    if (t + 2 < nk) {
      int sb = (cb == 0) ? 2 : cb - 1;
      STAGE(sb, (t + 2) << 5);
    }
    short8 a[4], b[4];
#pragma unroll
    for (int mi = 0; mi < 4; ++mi) {
      int ra = wm * 64 + mi * 16 + l16;
      a[mi] = *(const short8*)(ASB(cb) + (ra << 5) + ((qg ^ rswz) << 3));
    }
#pragma unroll
    for (int ni = 0; ni < 4; ++ni) {
      int n = wn * 64 + ni * 16 + l16;
      b[ni] = *(const short8*)(BSB(cb) + (n << 5) + ((qg ^ rswz) << 3));
    }
    __builtin_amdgcn_s_setprio(1);
#pragma unroll
    for (int ni = 0; ni < 4; ++ni)
#pragma unroll
      for (int mi = 0; mi < 4; ++mi)
        acc[mi][ni] = __builtin_amdgcn_mfma_f32_16x16x32_bf16(a[mi], b[ni], acc[mi][ni], 0, 0, 0);
    __builtin_amdgcn_s_setprio(0);
    cb = (cb == 2) ? 0 : cb + 1;
  }
  __builtin_amdgcn_s_barrier();
  if (!c32) {
    short* wreg = Ls + w * 4096;
#pragma unroll
    for (int ni = 0; ni < 4; ++ni) {
      float bvv = bias ? loadf(bias, n0 + wn * 64 + ni * 16 + l16, f32) : 0.0f;
#pragma unroll
      for (int mi = 0; mi < 4; ++mi)
#pragma unroll
        for (int r = 0; r < 4; ++r)
          wreg[(mi * 16 + qg * 4 + r) * 64 + ni * 16 + l16] = f2b(acc[mi][ni][r] + bvv);
    }
    asm volatile("s_waitcnt lgkmcnt(0)" ::: "memory");
#pragma unroll
    for (int j = 0; j < 8; ++j) {
      int row = j * 8 + (lane >> 3);
      int col = (lane & 7) * 8;
      short8 v = *(const short8*)(wreg + row * 64 + col);
      *(short8*)((short*)C + (size_t)(crow0 + wm * 64 + row) * N + n0 + wn * 64 + col) = v;
    }
  } else {
    float* wregf = (float*)(Ls) + w * 2048;
#pragma unroll
    for (int half = 0; half < 2; ++half) {
#pragma unroll
      for (int nh = 0; nh < 2; ++nh) {
        int ni = half * 2 + nh;
        float bvv = bias ? loadf(bias, n0 + wn * 64 + ni * 16 + l16, f32) : 0.0f;
#pragma unroll
        for (int mi = 0; mi < 4; ++mi)
#pragma unroll
          for (int r = 0; r < 4; ++r)
            wregf[(mi * 16 + qg * 4 + r) * 32 + nh * 16 + l16] = acc[mi][ni][r] + bvv;
      }
      asm volatile("s_waitcnt lgkmcnt(0)" ::: "memory");
#pragma unroll
      for (int j = 0; j < 8; ++j) {
        int row = j * 8 + (lane >> 3);
        int c4 = (lane & 7) * 4;
        float4 v = *(const float4*)(wregf + row * 32 + c4);
        *(float4*)((float*)C + (size_t)(crow0 + wm * 64 + row) * N + n0 + wn * 64 + half * 32 + c4) = v;
      }
      asm volatile("s_waitcnt lgkmcnt(0)" ::: "memory");
    }
  }
#undef ASB
#undef BSB
}

// ---------- RMSNorm + RoPE: one wave per head; q scaled by rsqrt(128)*log2(e).
__global__ __launch_bounds__(512)
void norm_rope(short* __restrict__ qkv, const int* __restrict__ ids,
               const void* __restrict__ nqw, const void* __restrict__ nkw,
               const void* __restrict__ naqw, const void* __restrict__ nakw,
               const int* __restrict__ dflag) {
  const bool f32 = (*dflag != 0);
  const int t = blockIdx.x, wv = threadIdx.x >> 6, lane = threadIdx.x & 63;
  const bool txt = t < 512;
  int p = lane, axis; float expo;
  if (p < 8)       { axis = 0; expo = (float)(2 * p) * (1.0f / 16.0f); }
  else if (p < 36) { axis = 1; expo = (float)(2 * (p - 8)) * (1.0f / 56.0f); }
  else             { axis = 2; expo = (float)(2 * (p - 36)) * (1.0f / 56.0f); }
  float freq = __expf(-expo * 9.210340371976184f);
  float ang = (float)ids[t * 3 + axis] * freq;
  float s, c; sincosf(ang, &s, &c);
  const void* qw = txt ? naqw : nqw;
  const void* kw = txt ? nakw : nkw;
  float w0q = loadf(qw, 2 * lane, f32), w1q = loadf(qw, 2 * lane + 1, f32);
  float w0k = loadf(kw, 2 * lane, f32), w1k = loadf(kw, 2 * lane + 1, f32);
  const float QS = 0.08838834764831845f * 1.4426950408889634f;
#pragma unroll
  for (int i = 0; i < 3; ++i) {
    int h = wv + 8 * i;
    short* qp = qkv + (size_t)t * 9216 + h * 128 + 2 * lane;
    short* kp = qp + 3072;
    union { unsigned u; short sh[2]; } qv, kv;
    qv.u = *(const unsigned*)qp;
    kv.u = *(const unsigned*)kp;
    float q0 = b2f(qv.sh[0]), q1 = b2f(qv.sh[1]);
    float k0 = b2f(kv.sh[0]), k1 = b2f(kv.sh[1]);
    float sq = q0 * q0 + q1 * q1, sk = k0 * k0 + k1 * k1;
#pragma unroll
    for (int o = 1; o < 64; o <<= 1) { sq += __shfl_xor(sq, o); sk += __shfl_xor(sk, o); }
    float rq = rsqrtf(sq * (1.0f / 128.0f) + 1e-5f);
    float rk = rsqrtf(sk * (1.0f / 128.0f) + 1e-5f);
    float qn0 = q0 * rq * w0q, qn1 = q1 * rq * w1q;
    float kn0 = k0 * rk * w0k, kn1 = k1 * rk * w1k;
    float qo0 = qn0 * c - qn1 * s, qo1 = qn1 * c + qn0 * s;
    float ko0 = kn0 * c - kn1 * s, ko1 = kn1 * c + kn0 * s;
    union { unsigned u; short sh[2]; } qo, ko;
    qo.sh[0] = f2b(qo0 * QS);
    qo.sh[1] = f2b(qo1 * QS);
    ko.sh[0] = f2b(ko0); ko.sh[1] = f2b(ko1);
    *(unsigned*)qp = qo.u;
    *(unsigned*)kp = ko.u;
  }
}

// ---------- flash attention v10 (measured-best: Q128/KB128, 2 blocks/CU,
// Pw pitch-32 + XOR). R24 lesson: Pw bank re-map cut conflicts 9% but cost
// +2us (addressing ALU, +1 VGPR) — Pw conflicts are NOT on the critical path.
// The kernel is barrier/latency-bound; this is its measured floor.
__global__ __launch_bounds__(512, 2)
void attn_fa(const short* __restrict__ qkv, short* __restrict__ attn) {
  __shared__ short KVs[2][128 * 128];   // 64 KB: K tiles; V^T overwrites in place
  __shared__ short Pw[8][512];          // 8 KB: per-wave P chunk (16 rows x 32 keys)
  const int wgid = blockIdx.x;
  const int xcd = wgid & 7, slot = wgid >> 3;   // 60 slots/XCD
  const int h = xcd * 3 + slot / 20;            // 3 heads per XCD (L2-resident K/V)
  const int qt = slot % 20;
  const int tid = threadIdx.x, lane = tid & 63, w = tid >> 6;  // 8 waves
  const int qg = lane >> 4, l16 = lane & 15;
  const int lr = lane >> 4, lc = lane & 15;
  const int q0 = qt << 7;
  const int sc = tid & 15;
  const int srow5 = (tid >> 4) & 15, half = tid >> 8;

  const short* Qg  = qkv + (size_t)q0 * 9216 + h * 128;
  const short* Kg0 = qkv + 3072 + h * 128;
  const short* Vg0 = qkv + 6144 + h * 128;

  // ---- prologue: K(0) gloads FIRST (drained by vmcnt(8)), then Q regs, V regs
#pragma unroll
  for (int j = 0; j < 4; ++j) {
    int row = j * 32 + w * 4 + lr;
    gload16(Kg0 + (size_t)row * 9216 + ((lc ^ (row & 7)) << 3),
            &KVs[0][(j * 32 + w * 4) * 128]);
  }
  short8 aq[4];
#pragma unroll
  for (int kc = 0; kc < 4; ++kc)
    aq[kc] = *(const short8*)(Qg + (size_t)(w * 16 + l16) * 9216 + kc * 32 + qg * 8);
  short8 vr[4];
#pragma unroll
  for (int j = 0; j < 4; ++j) {
    int row = half * 64 + j * 16 + srow5;
    vr[j] = *(const short8*)(Vg0 + (size_t)row * 9216 + sc * 8);
  }
  asm volatile("s_waitcnt vmcnt(8) lgkmcnt(0)" ::: "memory");  // K(0) done; Q,V in flight
  __builtin_amdgcn_s_barrier();

  floatx4 acc_o[8];
#pragma unroll
  for (int nd = 0; nd < 8; ++nd) acc_o[nd] = (floatx4){0.f, 0.f, 0.f, 0.f};
  float m_i[4], l_i[4];
#pragma unroll
  for (int r = 0; r < 4; ++r) { m_i[r] = -1e30f; l_i[r] = 0.0f; }

  for (int kt = 0; kt < 20; ++kt) {
    const int cb = kt & 1;
    asm volatile("s_waitcnt vmcnt(4) lgkmcnt(0)" ::: "memory");  // K(kt) landed; V(kt) in flight
    __builtin_amdgcn_s_barrier();
    if (kt < 19) {
      const short* Kg = qkv + ((size_t)(kt + 1) * 128) * 9216 + 3072 + h * 128;
#pragma unroll
      for (int j = 0; j < 4; ++j) {
        int row = j * 32 + w * 4 + lr;
        gload16(Kg + (size_t)row * 9216 + ((lc ^ (row & 7)) << 3),
                &KVs[1 - cb][(j * 32 + w * 4) * 128]);
      }
    }
    // ---- QK^T: 16 q-rows x 128 keys (scores in log2 domain via q-scale)
    floatx4 acc_s[8];
#pragma unroll
    for (int ni = 0; ni < 8; ++ni) acc_s[ni] = (floatx4){0.f, 0.f, 0.f, 0.f};
    __builtin_amdgcn_s_setprio(1);
#pragma unroll
    for (int kc = 0; kc < 4; ++kc) {
#pragma unroll
      for (int ni = 0; ni < 8; ++ni) {
        int row = ni * 16 + l16;
        short8 b = *(const short8*)(&KVs[cb][row * 128 + (((kc * 4 + qg) ^ (row & 7)) << 3)]);
        acc_s[ni] = __builtin_amdgcn_mfma_f32_16x16x32_bf16(aq[kc], b, acc_s[ni], 0, 0, 0);
      }
    }
    __builtin_amdgcn_s_setprio(0);
    // ---- online softmax, exp2 domain, defer-rescale (T13)
    float mxv[4];
    bool need = false;
#pragma unroll
    for (int r = 0; r < 4; ++r) {
      float mx = acc_s[0][r];
#pragma unroll
      for (int ni = 1; ni < 8; ++ni) mx = fmaxf(mx, acc_s[ni][r]);
      mx = fmaxf(mx, __shfl_xor(mx, 1));
      mx = fmaxf(mx, __shfl_xor(mx, 2));
      mx = fmaxf(mx, __shfl_xor(mx, 4));
      mx = fmaxf(mx, __shfl_xor(mx, 8));
      mxv[r] = mx;
      need = need || (mx > m_i[r] + 8.0f);
    }
    if (__ballot(need)) {
#pragma unroll
      for (int r = 0; r < 4; ++r) {
        float mn = fmaxf(m_i[r], mxv[r]);
        float al = __builtin_amdgcn_exp2f(m_i[r] - mn);
        m_i[r] = mn;
        l_i[r] *= al;
#pragma unroll
        for (int nd = 0; nd < 8; ++nd) acc_o[nd][r] *= al;
      }
    }
    // pkr[r][kc]: bf16x2 of (pv[2kc], pv[2kc+1]) — P chunk kc, in-chunk t'=2*l16(+1)
    unsigned pkr[4][4];
#pragma unroll
    for (int r = 0; r < 4; ++r) {
      float pv[8];
      float rs = 0.f;
#pragma unroll
      for (int ni = 0; ni < 8; ++ni) {
        pv[ni] = __builtin_amdgcn_exp2f(acc_s[ni][r] - m_i[r]);
        rs += pv[ni];
      }
#pragma unroll
      for (int kc = 0; kc < 4; ++kc) pkr[r][kc] = cvtpk(pv[2 * kc], pv[2 * kc + 1]);
      rs += __shfl_xor(rs, 1); rs += __shfl_xor(rs, 2);
      rs += __shfl_xor(rs, 4); rs += __shfl_xor(rs, 8);
      l_i[r] += rs;
    }
    asm volatile("s_waitcnt lgkmcnt(0)" ::: "memory");
    __builtin_amdgcn_s_barrier();   // QK^T reads of KVs[cb] done
    // ---- commit V^T(kt) into KVs[cb]: token r -> chunk r>>5, in-chunk
    // t' = 2*(r&15) + ((r>>4)&1).
#pragma unroll
    for (int u = 0; u < 8; ++u) {
      int d = sc * 8 + u;
      int xr = (d & 7) ^ ((d >> 3) & 7);
#pragma unroll
      for (int jp = 0; jp < 2; ++jp) {
        int kcw = 2 * half + jp;
        int g = kcw * 4 + (srow5 >> 2);
        union { unsigned uu; short sh[2]; } pk;
        pk.sh[0] = vr[2 * jp][u]; pk.sh[1] = vr[2 * jp + 1][u];
        *(unsigned*)(&KVs[cb][d * 128 + ((g ^ xr) << 3) + ((2 * srow5) & 7)]) = pk.uu;
      }
    }
    if (kt < 19) {
      const short* Vg = qkv + ((size_t)(kt + 1) * 128) * 9216 + 6144 + h * 128;
#pragma unroll
      for (int j = 0; j < 4; ++j) {
        int row = half * 64 + j * 16 + srow5;
        vr[j] = *(const short8*)(Vg + (size_t)row * 9216 + sc * 8);
      }
    }
    asm volatile("s_waitcnt lgkmcnt(0)" ::: "memory");
    __builtin_amdgcn_s_barrier();
    // ---- PV: per kc spill P chunk to wave-private Pw, read A-frag, 8 MFMA.
    __builtin_amdgcn_s_setprio(1);
#pragma unroll
    for (int kc = 0; kc < 4; ++kc) {
#pragma unroll
      for (int r = 0; r < 4; ++r)
        *(unsigned*)(&Pw[w][(qg * 4 + r) * 32 + ((l16 ^ (qg << 2)) << 1)]) = pkr[r][kc];
      short8 ap = *(const short8*)(&Pw[w][l16 * 32 + ((qg ^ (l16 >> 2)) << 3)]);
#pragma unroll
      for (int nd = 0; nd < 8; ++nd) {
        int d = nd * 16 + l16;
        int chn = (kc * 4 + qg) ^ (d & 7) ^ ((d >> 3) & 7);
        short8 b = *(const short8*)(&KVs[cb][d * 128 + (chn << 3)]);
        acc_o[nd] = __builtin_amdgcn_mfma_f32_16x16x32_bf16(ap, b, acc_o[nd], 0, 0, 0);
      }
    }
    __builtin_amdgcn_s_setprio(0);
  }
  // ---- epilogue: normalize, transpose through KVs (freed), coalesced stores
  asm volatile("s_waitcnt lgkmcnt(0)" ::: "memory");
  __builtin_amdgcn_s_barrier();   // all PV reads done
  short* Es = &KVs[0][0];         // 128 rows x 128 shorts
  float inv[4];
#pragma unroll
  for (int r = 0; r < 4; ++r) inv[r] = 1.0f / l_i[r];
#pragma unroll
  for (int nd = 0; nd < 8; ++nd)
#pragma unroll
    for (int r = 0; r < 4; ++r) {
      int row = w * 16 + qg * 4 + r;
      Es[row * 128 + nd * 16 + l16] = f2b(acc_o[nd][r] * inv[r]);
    }
  asm volatile("s_waitcnt lgkmcnt(0)" ::: "memory");   // wave-private rows
#pragma unroll
  for (int j = 0; j < 4; ++j) {
    int rrow = w * 16 + j * 4 + qg;
    short8 vv = *(const short8*)(Es + rrow * 128 + l16 * 8);
    *(short8*)(attn + (size_t)(q0 + rrow) * 3072 + h * 128 + l16 * 8) = vv;
  }
}

extern "C" void kernel_launch(void* const* d_in, const int* in_sizes, int n_in,
                              void* d_out, int out_size, void* d_ws, size_t ws_size,
                              hipStream_t stream) {
  (void)in_sizes; (void)n_in; (void)out_size;
  const void* hidden    = d_in[0];
  const void* enc       = d_in[1];
  const int*  ids       = (const int*)d_in[2];
  const void* w_qkv     = d_in[3];
  const void* w_add_qkv = d_in[4];
  const void* b_add_qkv = d_in[5];
  const void* w_out     = d_in[6];
  const void* b_out     = d_in[7];
  const void* w_add_out = d_in[8];
  const void* b_add_out = d_in[9];
  const void* nqw  = d_in[10];
  const void* nkw  = d_in[11];
  const void* naqw = d_in[12];
  const void* nakw = d_in[13];

  int*   dflag = (int*)d_ws;
  short* qkv   = (short*)((char*)d_ws + 256);   // [2560][9216] bf16
  short* attnB = qkv + (size_t)2560 * 9216;     // [2560][3072] bf16

  short* pool  = attnB + (size_t)2560 * 3072;
  const long n_hid  = 2048L * 3072;
  const long n_enc  = 512L * 3072;
  const long n_wqkv = 3072L * 9216;
  const long n_wout = 3072L * 3072;
  short* xb   = pool;                    // [2560][3072]
  short* wqb  = xb + n_enc + n_hid;      // w_qkv^T    [9216][3072]
  short* waqb = wqb + n_wqkv;            // w_add_qkv^T[9216][3072]
  short* wob  = waqb + n_wqkv;           // w_out^T    [3072][3072]
  short* waob = wob + n_wout;            // w_add_out^T[3072][3072]
  const size_t REQ = 256 + 2 * ((size_t)2560 * 9216 + (size_t)2560 * 3072 +
                                n_hid + n_enc + 2 * n_wqkv + 2 * n_wout);

  detect_dtype<<<1, 256, 0, stream>>>((const unsigned short*)w_qkv, dflag);

  if (ws_size >= REQ) {
    // single conversion launch: 18432 transpose blocks + 1024 copy blocks
    cvt_all<<<dim3(19456), 256, 0, stream>>>(
        w_qkv, wqb, w_add_qkv, waqb, w_out, wob, w_add_out, waob,
        enc, n_enc / 8, hidden, n_hid / 8, xb, dflag);

    // merged QKV projection, 256-row tiles: y<2 -> enc (bias), y>=2 -> hidden
    gemm_bf2<<<dim3(72, 10), 256, 0, stream>>>(
        xb, waqb, b_add_qkv, 0, 0, 2, wqb, nullptr, 512, 512,
        qkv, 9216, 3072, dflag, 0);
    norm_rope<<<dim3(2560), 512, 0, stream>>>(qkv, ids, nqw, nkw, naqw, nakw, dflag);
    // attention: 480 blocks = 24 heads x 20 q-tiles of 128, 2 blocks/CU
    attn_fa<<<dim3(480), 512, 0, stream>>>(qkv, attnB);
    // merged out-proj, 128-row tiles: y<16 img, y>=16 enc
    gemm_bf128<<<dim3(24, 20), 256, 0, stream>>>(
        attnB, wob, b_out, 512, 0, 16, waob, b_add_out, 0, 2048,
        d_out, 3072, 3072, dflag, 1);
  } else {
    gemm_bt<<<dim3(72, 4), 256, 0, stream>>>(enc, 0, w_add_qkv, b_add_qkv, qkv, 0, 9216, 3072, dflag, 1, 0);
    gemm_bt<<<dim3(72, 16), 256, 0, stream>>>(hidden, 0, w_qkv, nullptr, qkv, 512, 9216, 3072, dflag, 1, 0);
    norm_rope<<<dim3(2560), 512, 0, stream>>>(qkv, ids, nqw, nkw, naqw, nakw, dflag);
    attn_fa<<<dim3(480), 512, 0, stream>>>(qkv, attnB);
    gemm_bt<<<dim3(24, 16), 256, 0, stream>>>(attnB, 512, w_out, b_out, d_out, 0, 3072, 3072, dflag, 0, 1);
    gemm_bt<<<dim3(24, 4), 256, 0, stream>>>(attnB, 0, w_add_out, b_add_out, d_out, 2048, 3072, 3072, dflag, 0, 1);
  }
}